// Round 21
// baseline (215.933 us; speedup 1.0000x reference)
//
#include <hip/hip_runtime.h>

typedef unsigned short ushort_t;
typedef unsigned char uchar;
typedef unsigned int uint32;
typedef __attribute__((ext_vector_type(8))) short short8;
typedef __attribute__((ext_vector_type(4))) float f32x4;
typedef __attribute__((ext_vector_type(16))) float f32x16;
typedef __attribute__((ext_vector_type(2))) unsigned int u32x2;
typedef __attribute__((ext_vector_type(2))) long long i64x2;
typedef __attribute__((ext_vector_type(8))) int i32x8;

#define BATCH 8
#define NPTS 12544
#define CC 192
#define KCL 784
#define N2 3136
#define TOTPTS 25088        // BATCH*N2
#define OUT_FEAT_OFF 50176
#define OUT_MASK_OFF 9683968
#define FNEG 3.402823466e38f
#define PANEL 786432        // 128*6144 bytes per A panel

__device__ __forceinline__ ushort_t f2bf(float f) {
    union { float f; uint32 u; } v; v.f = f;
    uint32 u = v.u;
    uint32 r = (u + 0x7FFFu + ((u >> 16) & 1u)) >> 16;
    return (ushort_t)r;
}
// tanh-form gelu (|diff vs exact erf-gelu| <= ~3e-3; negligible vs fp8 path error)
__device__ __forceinline__ float gelu_fast(float x) {
    float y = 0.7978845608f * x * (1.f + 0.044715f * x * x);
    float e = __expf(2.f * y);
    float t = 1.f - 2.f / (e + 1.f);
    return 0.5f * x * (1.f + t);
}
__device__ __forceinline__ uchar f2e4m3(float f) {
    return (uchar)(__builtin_amdgcn_cvt_pk_fp8_f32(f, f, 0, false) & 0xFF);
}

__device__ __forceinline__ void gld16(const void* g, void* l) {
    __builtin_amdgcn_global_load_lds((const __attribute__((address_space(1))) void*)g,
                                     (__attribute__((address_space(3))) void*)l, 16, 0, 0);
}

// JAX threefry2x32 with key = (0, 42)
__device__ __forceinline__ void threefry(uint32 x0, uint32 x1, uint32& y0, uint32& y1) {
    const uint32 k0 = 0u, k1 = 42u;
    const uint32 k2 = 0u ^ 42u ^ 0x1BD11BDAu;
#define ROT(v,r) (((v) << (r)) | ((v) >> (32 - (r))))
#define RND(r) { x0 += x1; x1 = ROT(x1, r); x1 ^= x0; }
    x0 += k0; x1 += k1;
    RND(13) RND(15) RND(26) RND(6)
    x0 += k1; x1 += k2 + 1u;
    RND(17) RND(29) RND(16) RND(24)
    x0 += k2; x1 += k0 + 2u;
    RND(13) RND(15) RND(26) RND(6)
    x0 += k0; x1 += k1 + 3u;
    RND(17) RND(29) RND(16) RND(24)
    x0 += k1; x1 += k2 + 4u;
    RND(13) RND(15) RND(26) RND(6)
    x0 += k2; x1 += k0 + 5u;
    y0 = x0; y1 = x1;
#undef RND
#undef ROT
}

// ---------------- points2img scatter + 2x downsample ----------------
__global__ void k_scatter(const float* __restrict__ pos, int* __restrict__ img)
{
    int t = blockIdx.x * 256 + threadIdx.x;
    int b = t / NPTS, n = t - b * NPTS;
    int x = (int)pos[(size_t)t * 2];
    int y = (int)pos[(size_t)t * 2 + 1];
    img[(size_t)b * NPTS + y * 112 + x] = n;
}

__global__ void k_down(const int* __restrict__ img, int* __restrict__ idxa)
{
    int q = blockIdx.x * 256 + threadIdx.x;
    int b = q / N2, p2 = q - b * N2;
    int r = p2 / 56, c = p2 - r * 56;
    idxa[q] = img[(size_t)b * NPTS + (2 * r) * 112 + 2 * c];
}

// ---------------- lin_W -> fp8 B-tiles: [kc 0..95][row n 0..383][64B], swizzled ----------------
__global__ __launch_bounds__(256) void k_linT(const float* __restrict__ W, uchar* __restrict__ T)
{
    __shared__ float tile[64][65];
    int q0 = blockIdx.x * 64, n0 = blockIdx.y * 64;
    for (int s = 0; s < 16; ++s) {
        int id = threadIdx.x + s * 256;
        int i = id >> 6, j = id & 63;
        int q = q0 + i;
        int w = q & 63;
        int kap = (q & ~63) + 8 * ((w >> 4) & 3) + 32 * ((w >> 3) & 1) + (w & 7);
        int c = kap >> 5, k = kap & 31;
        tile[i][j] = W[(size_t)(k * 192 + c) * 384 + n0 + j];
    }
    __syncthreads();
    for (int s = 0; s < 16; ++s) {
        int id = threadIdx.x + s * 256;
        int jj = id >> 6, ii = id & 63;
        int q = q0 + ii, n = n0 + jj;
        int gp = ((q >> 4) & 3) ^ ((n >> 1) & 3);
        T[(size_t)(q >> 6) * 24576 + n * 64 + gp * 16 + (q & 15)] = f2e4m3(tile[ii][jj]);
    }
}

// ---------------- precompute f1W MFMA B-fragments (bf16): frag[ks][w][lane][j] ----------------
__global__ __launch_bounds__(256) void k_prep(const float* __restrict__ f1W, ushort_t* __restrict__ frag)
{
    int t = blockIdx.x * 256 + threadIdx.x;   // 12288 total
    int j = t & 7;
    int lane = (t >> 3) & 63;
    int w = (t >> 9) & 3;
    int ks = t >> 11;
    int k = ks * 32 + (lane >> 4) * 8 + j;
    int o = w * 16 + (lane & 15);
    frag[t] = f2bf(f1W[k * 64 + o]);
}

// ---------------- per-point: ONE WAVE PER POINT, fused LayerNorm, MFMA agg ----------------
__global__ __launch_bounds__(256) void k_point(
    const float* __restrict__ pos, const float* __restrict__ feat,
    const float* __restrict__ maskp,
    const int* __restrict__ massign, const int* __restrict__ memidx,
    const float* __restrict__ cmaskp,
    const int* __restrict__ idxarr, const ushort_t* __restrict__ f1frag,
    const float* __restrict__ norm_g, const float* __restrict__ norm_b,
    const float* __restrict__ w1W, const float* __restrict__ w1b,
    const float* __restrict__ lng, const float* __restrict__ lnb,
    const float* __restrict__ f1b,
    const float* __restrict__ f2W, const float* __restrict__ f2b,
    uchar* __restrict__ agg, float* __restrict__ outbuf, int p0)
{
    __shared__ __align__(16) ushort_t frelb[4][4][200];
    __shared__ __align__(16) float wsm[4][4][32];
    __shared__ __align__(16) float hbuf[4][4][64];
    __shared__ __align__(8) ushort_t fgT[4][192][4];   // bf16 FG columns, per wave

    int tid = threadIdx.x;
    int wave = tid >> 6, lane = tid & 63;
    int l15 = lane & 15, l4 = lane >> 4;
    int l31 = lane & 31, hh = lane >> 5;
    int point = p0 + blockIdx.x * 4 + wave;
    int b = point / N2;
    size_t browbase = (size_t)b * NPTS;
    int idx_pt = idxarr[point];

    // phase 1: scoring, 2 items per lane (items lane, lane+64)
    int j8 = lane >> 4, i16 = lane & 15;
    int maj_lo = massign[(browbase + idx_pt) * 8 + j8];
    int maj_hi = massign[(browbase + idx_pt) * 8 + 4 + j8];
    size_t roff_lo = ((size_t)b * KCL + maj_lo) * 16 + i16;
    size_t roff_hi = ((size_t)b * KCL + maj_hi) * 16 + i16;
    int mv_lo = memidx[roff_lo], mv_hi = memidx[roff_hi];
    float cv_lo = cmaskp[roff_lo]; if (mv_lo == idx_pt) cv_lo = 0.f;
    float cv_hi = cmaskp[roff_hi]; if (mv_hi == idx_pt) cv_hi = 0.f;
    float pr_lo = fmaxf(cv_lo, 1e-5f), pr_hi = fmaxf(cv_hi, 1e-5f);
    uint32 y0, y1;
    threefry(0u, (uint32)point * 128u + (uint32)lane, y0, y1);
    uint32 bits_lo = y0 ^ y1;
    threefry(0u, (uint32)point * 128u + (uint32)lane + 64u, y0, y1);
    uint32 bits_hi = y0 ^ y1;
    union { uint32 u; float f; } cu;
    cu.u = (bits_lo >> 9) | 0x3f800000u; float u_lo = cu.f - 1.0f;
    cu.u = (bits_hi >> 9) | 0x3f800000u; float u_hi = cu.f - 1.0f;
    float a0 = logf(pr_lo) - logf(-logf(u_lo + 1e-20f) + 1e-20f);
    float a1 = logf(pr_hi) - logf(-logf(u_hi + 1e-20f) + 1e-20f);

    float pdx = pos[(browbase + idx_pt) * 2];
    float pdy = pos[(browbase + idx_pt) * 2 + 1];
    if (lane == 0) {
        outbuf[OUT_MASK_OFF + point] = maskp[browbase + idx_pt];
        outbuf[(size_t)point * 2]     = floorf(pdx * 0.5f);
        outbuf[(size_t)point * 2 + 1] = floorf(pdy * 0.5f);
    }

    // phase 2: in-wave top-4 butterfly (ties -> lower index)
    float aa0 = a0, aa1 = a1;
    float tops[4]; int topi[4];
#pragma unroll
    for (int pass = 0; pass < 4; ++pass) {
        float s; int si;
        if (aa0 >= aa1) { s = aa0; si = lane; } else { s = aa1; si = lane + 64; }
#pragma unroll
        for (int d = 32; d >= 1; d >>= 1) {
            float s2 = __shfl_xor(s, d, 64);
            int i2 = __shfl_xor(si, d, 64);
            if (s2 > s || (s2 == s && i2 < si)) { s = s2; si = i2; }
        }
        tops[pass] = s; topi[pass] = si;
        if (si == lane) aa0 = -FNEG;
        if (si == lane + 64) aa1 = -FNEG;
    }
    int mc0 = (topi[0] < 64) ? __shfl(mv_lo, topi[0], 64) : __shfl(mv_hi, topi[0] - 64, 64);
    int mc1 = (topi[1] < 64) ? __shfl(mv_lo, topi[1], 64) : __shfl(mv_hi, topi[1] - 64, 64);
    int mc2 = (topi[2] < 64) ? __shfl(mv_lo, topi[2], 64) : __shfl(mv_hi, topi[2] - 64, 64);
    if (tops[2] - tops[3] < 1e-4f) {
        double b0 = log((double)pr_lo) - log(-log((double)u_lo + 1e-20) + 1e-20);
        double b1 = log((double)pr_hi) - log(-log((double)u_hi + 1e-20) + 1e-20);
        int mcs[3];
#pragma unroll
        for (int pass = 0; pass < 3; ++pass) {
            double s; int si;
            if (b0 >= b1) { s = b0; si = lane; } else { s = b1; si = lane + 64; }
            for (int d = 32; d >= 1; d >>= 1) {
                double s2 = __shfl_xor(s, d, 64);
                int i2 = __shfl_xor(si, d, 64);
                if (s2 > s || (s2 == s && i2 < si)) { s = s2; si = i2; }
            }
            mcs[pass] = (si < 64) ? __shfl(mv_lo, si, 64) : __shfl(mv_hi, si - 64, 64);
            if (si == lane) b0 = -1.0e300;
            if (si == lane + 64) b1 = -1.0e300;
        }
        mc0 = mcs[0]; mc1 = mcs[1]; mc2 = mcs[2];
    }
    int rows[4] = { mc0, mc1, mc2, idx_pt };

    // phase 3: gather raw feat rows + fused LayerNorm (in-wave reductions); prel
    float ng0 = norm_g[lane], ng1 = norm_g[lane + 64], ng2 = norm_g[lane + 128];
    float nb0 = norm_b[lane], nb1 = norm_b[lane + 64], nb2 = norm_b[lane + 128];
    float fgv[4][3];
    float prelx[4], prely[4];
#pragma unroll
    for (int m = 0; m < 4; ++m) {
        size_t rbase = (browbase + rows[m]) * (size_t)CC;
        float v0 = feat[rbase + lane];
        float v1 = feat[rbase + lane + 64];
        float v2 = feat[rbase + lane + 128];
        float s = v0 + v1 + v2;
#pragma unroll
        for (int d = 32; d >= 1; d >>= 1) s += __shfl_xor(s, d, 64);
        float mu = s * (1.f / 192.f);
        float d0 = v0 - mu, d1 = v1 - mu, d2 = v2 - mu;
        float q = d0 * d0 + d1 * d1 + d2 * d2;
#pragma unroll
        for (int d = 32; d >= 1; d >>= 1) q += __shfl_xor(q, d, 64);
        float rstd = 1.f / sqrtf(q * (1.f / 192.f) + 1e-5f);
        fgv[m][0] = d0 * rstd * ng0 + nb0;
        fgv[m][1] = d1 * rstd * ng1 + nb1;
        fgv[m][2] = d2 * rstd * ng2 + nb2;
        prelx[m] = pos[(browbase + rows[m]) * 2]     - pdx;
        prely[m] = pos[(browbase + rows[m]) * 2 + 1] - pdy;
    }

    // phase 4a: frelb + fgT build (this wave's private slices)
#pragma unroll
    for (int jj = 0; jj < 3; ++jj) {
        int c = lane + jj * 64;
#pragma unroll
        for (int m = 0; m < 4; ++m)
            frelb[wave][m][c] = f2bf(fgv[m][jj] - fgv[3][jj]);
        uint32 lo = ((uint32)f2bf(fgv[1][jj]) << 16) | (uint32)f2bf(fgv[0][jj]);
        uint32 hi = ((uint32)f2bf(fgv[3][jj]) << 16) | (uint32)f2bf(fgv[2][jj]);
        *(u32x2*)(&fgT[wave][c][0]) = (u32x2){lo, hi};
    }

    // phase 4b: pos MLP, 2 m-rows per lane
    {
        int kk = lane & 31;
        int mbase = lane >> 5;
#pragma unroll
        for (int t = 0; t < 2; ++t) {
            int m = mbase + 2 * t;
            float px = (m == 0) ? prelx[0] : (m == 1) ? prelx[1] : (m == 2) ? prelx[2] : prelx[3];
            float py = (m == 0) ? prely[0] : (m == 1) ? prely[1] : (m == 2) ? prely[2] : prely[3];
            float pre = px * w1W[kk] + py * w1W[32 + kk] + w1b[kk];
            float s = pre;
            for (int d = 16; d >= 1; d >>= 1) s += __shfl_xor(s, d, 64);
            float mu = s * (1.f / 32.f);
            float dv = pre - mu;
            float vs = dv * dv;
            for (int d = 16; d >= 1; d >>= 1) vs += __shfl_xor(vs, d, 64);
            float var = vs * (1.f / 32.f);
            float nv = dv / sqrtf(var + 1e-5f) * lng[kk] + lnb[kk];
            wsm[wave][m][kk] = gelu_fast(nv);
        }
    }

    // phase 5: gate MFMA — one wave does all 4 o-tiles (24 MFMAs)
    f32x4 acc[4];
#pragma unroll
    for (int w = 0; w < 4; ++w) acc[w] = (f32x4){0.f, 0.f, 0.f, 0.f};
#pragma unroll
    for (int ks = 0; ks < 6; ++ks) {
        short8 av;
        if (l15 < 4) av = *(const short8*)(&frelb[wave][l15][ks * 32 + l4 * 8]);
        else av = (short8){0,0,0,0,0,0,0,0};
#pragma unroll
        for (int w = 0; w < 4; ++w) {
            short8 bv = *(const short8*)(f1frag + ((size_t)(ks * 4 + w) * 64 + lane) * 8);
            acc[w] = __builtin_amdgcn_mfma_f32_16x16x32_bf16(av, bv, acc[w], 0, 0, 0);
        }
    }
    if (l4 == 0) {
#pragma unroll
        for (int w = 0; w < 4; ++w)
            *(f32x4*)(&hbuf[wave][w][l15 * 4]) = acc[w];
    }
    float fv = 0.f;
#pragma unroll
    for (int w = 0; w < 4; ++w) {
        float hv = hbuf[wave][w][lane];              // o = w*16 + (lane>>2), m = lane&3
        int o = w * 16 + (lane >> 2);
        fv += gelu_fast(hv + f1b[o]) * f2W[o];
    }
#pragma unroll
    for (int d = 4; d <= 32; d <<= 1) fv += __shfl_xor(fv, d, 64);
    fv = 1.f / (1.f + __expf(-(fv + f2b[0])));
    float fwv0 = __shfl(fv, (lane & ~3) | 0, 64);
    float fwv1 = __shfl(fv, (lane & ~3) | 1, 64);
    float fwv2 = __shfl(fv, (lane & ~3) | 2, 64);
    float fwv3 = __shfl(fv, (lane & ~3) | 3, 64);

    // phase 6: agg = (wsm*fwv)^T(32x4) @ FG(4x192) via 6x mfma 32x32x16 bf16 (K padded 4->16)
    // A: lane h=0: afr[j<4] = bf16(wsm[j][l31]*fwv_j); all else zero (zeros kill B's garbage half)
    {
        short8 afr = (short8){0,0,0,0,0,0,0,0};
        if (hh == 0) {
            afr[0] = (short)f2bf(wsm[wave][0][l31] * fwv0);
            afr[1] = (short)f2bf(wsm[wave][1][l31] * fwv1);
            afr[2] = (short)f2bf(wsm[wave][2][l31] * fwv2);
            afr[3] = (short)f2bf(wsm[wave][3][l31] * fwv3);
        }
        int mrow = point & 127;
        uchar* ppan = agg + (size_t)(point >> 7) * PANEL + (size_t)mrow * 64;
        int swz = (mrow >> 1) & 3;
#pragma unroll
        for (int tile = 0; tile < 6; ++tile) {
            int c = tile * 32 + l31;
            u32x2 bw = *(const u32x2*)(&fgT[wave][c][0]);
            short8 bfr = (short8){0,0,0,0,0,0,0,0};
            bfr[0] = (short)(bw[0] & 0xFFFFu);
            bfr[1] = (short)(bw[0] >> 16);
            bfr[2] = (short)(bw[1] & 0xFFFFu);
            bfr[3] = (short)(bw[1] >> 16);
            f32x16 dacc;
#pragma unroll
            for (int e = 0; e < 16; ++e) dacc[e] = 0.f;
            dacc = __builtin_amdgcn_mfma_f32_32x32x16_bf16(afr, bfr, dacc, 0, 0, 0);
            // D: col=l31 (-> c), row k = (reg&3) + 8*(reg>>2) + 4*hh; reg = 4r+i -> k = 8r+4hh+i
            size_t cb = (size_t)(c >> 1) * 8192 + 8 * (c & 1) + 4 * hh;
#pragma unroll
            for (int r = 0; r < 4; ++r) {
                uint32 w_ = __builtin_amdgcn_cvt_pk_fp8_f32(dacc[4 * r], dacc[4 * r + 1], 0, false);
                w_ = __builtin_amdgcn_cvt_pk_fp8_f32(dacc[4 * r + 2], dacc[4 * r + 3], w_, true);
                *(uint32*)(ppan + cb + (size_t)((r ^ swz) << 4)) = w_;
            }
        }
    }
}

// ---- GEMM: MX-scaled fp8 (scale=1.0), 32x32x64, BN=384, pre-tiled panels, 4-buf depth-3 ----
__global__ __launch_bounds__(256, 1) void k_gemm(const uchar* __restrict__ A,
    const uchar* __restrict__ BT, const float* __restrict__ bias,
    float* __restrict__ out, int p0)
{
    __shared__ __align__(16) uchar lds[4][32768];   // per buf: A[128][64] @0, B[384][64] @8192
    int tid = threadIdx.x;
    int wave = tid >> 6, lane = tid & 63;
    int l31 = lane & 31, h = lane >> 5;
    int m0 = blockIdx.x * 128;

    const uchar* Apan = A + ((size_t)(p0 >> 7) + blockIdx.x) * PANEL;

    f32x16 acc[4][3];
#pragma unroll
    for (int a = 0; a < 4; ++a)
#pragma unroll
        for (int bb = 0; bb < 3; ++bb)
#pragma unroll
            for (int e = 0; e < 16; ++e) acc[a][bb][e] = 0.f;

    auto stage = [&](int buf, int t) {
        const uchar* as = Apan + (size_t)t * 8192 + tid * 16;
        const uchar* bs = BT + (size_t)t * 24576 + tid * 16;
        uchar* ld = &lds[buf][0] + tid * 16;
#pragma unroll
        for (int i = 0; i < 2; ++i) gld16(as + i * 4096, ld + i * 4096);
#pragma unroll
        for (int i = 0; i < 6; ++i) gld16(bs + i * 4096, ld + 8192 + i * 4096);
    };

    int fsw = (l31 >> 1) & 3;
    int g0 = ((2 * h) ^ fsw) * 16;
    int g1 = ((2 * h + 1) ^ fsw) * 16;
    auto compute = [&](int t) {
        const uchar* Ab = &lds[t & 3][0];
        const uchar* Bb = Ab + 8192;
        union V8 { i64x2 hh[2]; i32x8 v; };
        V8 av[4], bv[3];
#pragma unroll
        for (int a = 0; a < 4; ++a) {
            int ro = (32 * a + l31) * 64;
            av[a].hh[0] = *(const i64x2*)(Ab + ro + g0);
            av[a].hh[1] = *(const i64x2*)(Ab + ro + g1);
        }
#pragma unroll
        for (int bb = 0; bb < 3; ++bb) {
            int ro = (wave * 96 + 32 * bb + l31) * 64;
            bv[bb].hh[0] = *(const i64x2*)(Bb + ro + g0);
            bv[bb].hh[1] = *(const i64x2*)(Bb + ro + g1);
        }
#pragma unroll
        for (int a = 0; a < 4; ++a)
#pragma unroll
            for (int bb = 0; bb < 3; ++bb)
                acc[a][bb] = __builtin_amdgcn_mfma_scale_f32_32x32x64_f8f6f4(
                    av[a].v, bv[bb].v, acc[a][bb], 0, 0, 0, 0x7F, 0, 0x7F);
    };

    // depth-3 pipeline, 8 gld16/thread/stage -> vmcnt(16) drains the oldest stage
    stage(0, 0);
    stage(1, 1);
    stage(2, 2);
    for (int t = 0; t < 94; ++t) {
        asm volatile("s_waitcnt vmcnt(16)" ::: "memory");
        __builtin_amdgcn_s_barrier();
        __builtin_amdgcn_sched_barrier(0);
        if (t < 93) stage((t + 3) & 3, t + 3);
        compute(t);
    }
    asm volatile("s_waitcnt vmcnt(8)" ::: "memory");
    __builtin_amdgcn_s_barrier();
    __builtin_amdgcn_sched_barrier(0);
    compute(94);
    asm volatile("s_waitcnt vmcnt(0)" ::: "memory");
    __builtin_amdgcn_s_barrier();
    __builtin_amdgcn_sched_barrier(0);
    compute(95);

    // C layout (32x32): col = lane&31, row = (reg&3) + 8*(reg>>2) + 4*(lane>>5)
#pragma unroll
    for (int a = 0; a < 4; ++a)
#pragma unroll
        for (int bb = 0; bb < 3; ++bb)
#pragma unroll
            for (int reg = 0; reg < 16; ++reg) {
                int rowm = (reg & 3) + 8 * (reg >> 2) + 4 * h;
                int rr = m0 + 32 * a + rowm;
                int cc = wave * 96 + 32 * bb + l31;
                out[(size_t)(p0 + rr) * 384 + cc] = acc[a][bb][reg] + bias[cc];
            }
}

extern "C" void kernel_launch(void* const* d_in, const int* in_sizes, int n_in,
                              void* d_out, int out_size, void* d_ws, size_t ws_size,
                              hipStream_t stream)
{
    const float* pos      = (const float*)d_in[0];
    const float* feat     = (const float*)d_in[1];
    const float* maskp    = (const float*)d_in[2];
    const int*   massign  = (const int*)d_in[4];
    const int*   memidx   = (const int*)d_in[5];
    const float* cmaskp   = (const float*)d_in[9];
    const float* norm_g   = (const float*)d_in[10];
    const float* norm_b   = (const float*)d_in[11];
    const float* w1W      = (const float*)d_in[12];
    const float* w1b      = (const float*)d_in[13];
    const float* lng      = (const float*)d_in[14];
    const float* lnb      = (const float*)d_in[15];
    const float* f1W      = (const float*)d_in[16];
    const float* f1b      = (const float*)d_in[17];
    const float* f2W      = (const float*)d_in[18];
    const float* f2b      = (const float*)d_in[19];
    const float* linW     = (const float*)d_in[20];
    const float* linb     = (const float*)d_in[21];

    char* ws = (char*)d_ws;
    int* img         = (int*)(ws);                      //    401,408 B
    int* idxa        = (int*)(ws + 401408);             //    100,352 B
    uchar* linT      = (uchar*)(ws + 501760);           //  2,359,296 B (fp8, tiled)
    ushort_t* f1frag = (ushort_t*)(ws + 2861056);       //     24,576 B
    uchar* agg       = (uchar*)(ws + 2885632);          // up to 154,140,672 B (fp8, panels)

    size_t avail = ws_size > 2885632 ? ws_size - 2885632 : 0;
    long long slabM = (long long)(avail / 6144);
    slabM &= ~127LL;
    if (slabM > TOTPTS) slabM = TOTPTS;
    if (slabM < 128) slabM = 128;

    hipMemsetAsync(img, 0, 401408, stream);
    k_scatter<<<392, 256, 0, stream>>>(pos, img);
    k_down<<<98, 256, 0, stream>>>(img, idxa);
    k_linT<<<dim3(96, 6), 256, 0, stream>>>(linW, linT);
    k_prep<<<48, 256, 0, stream>>>(f1W, f1frag);

    float* outF = (float*)d_out;
    for (int p0 = 0; p0 < TOTPTS; p0 += (int)slabM) {
        int cnt = TOTPTS - p0; if (cnt > (int)slabM) cnt = (int)slabM;
        k_point<<<cnt / 4, 256, 0, stream>>>(pos, feat, maskp, massign, memidx, cmaskp, idxa, f1frag,
                norm_g, norm_b, w1W, w1b, lng, lnb, f1b, f2W, f2b, agg, outF, p0);
        k_gemm<<<cnt / 128, 256, 0, stream>>>(agg, linT, linb, outF + OUT_FEAT_OFF, p0);
    }
}

// Round 22
// 187.709 us; speedup vs baseline: 1.1504x; 1.1504x over previous
//
#include <hip/hip_runtime.h>

typedef unsigned short ushort_t;
typedef unsigned char uchar;
typedef unsigned int uint32;
typedef __attribute__((ext_vector_type(8))) short short8;
typedef __attribute__((ext_vector_type(4))) float f32x4;
typedef __attribute__((ext_vector_type(16))) float f32x16;
typedef __attribute__((ext_vector_type(2))) unsigned int u32x2;
typedef __attribute__((ext_vector_type(2))) long long i64x2;
typedef __attribute__((ext_vector_type(8))) int i32x8;

#define BATCH 8
#define NPTS 12544
#define CC 192
#define KCL 784
#define N2 3136
#define TOTPTS 25088        // BATCH*N2
#define OUT_FEAT_OFF 50176
#define OUT_MASK_OFF 9683968
#define FNEG 3.402823466e38f
#define PANEL 786432        // 128*6144 bytes per A panel

__device__ __forceinline__ ushort_t f2bf(float f) {
    union { float f; uint32 u; } v; v.f = f;
    uint32 u = v.u;
    uint32 r = (u + 0x7FFFu + ((u >> 16) & 1u)) >> 16;
    return (ushort_t)r;
}
// tanh-form gelu (|diff vs exact erf-gelu| <= ~3e-3; negligible vs fp8 path error)
__device__ __forceinline__ float gelu_fast(float x) {
    float y = 0.7978845608f * x * (1.f + 0.044715f * x * x);
    float e = __expf(2.f * y);
    float t = 1.f - 2.f / (e + 1.f);
    return 0.5f * x * (1.f + t);
}
__device__ __forceinline__ uchar f2e4m3(float f) {
    return (uchar)(__builtin_amdgcn_cvt_pk_fp8_f32(f, f, 0, false) & 0xFF);
}

__device__ __forceinline__ void gld16(const void* g, void* l) {
    __builtin_amdgcn_global_load_lds((const __attribute__((address_space(1))) void*)g,
                                     (__attribute__((address_space(3))) void*)l, 16, 0, 0);
}

// JAX threefry2x32 with key = (0, 42)
__device__ __forceinline__ void threefry(uint32 x0, uint32 x1, uint32& y0, uint32& y1) {
    const uint32 k0 = 0u, k1 = 42u;
    const uint32 k2 = 0u ^ 42u ^ 0x1BD11BDAu;
#define ROT(v,r) (((v) << (r)) | ((v) >> (32 - (r))))
#define RND(r) { x0 += x1; x1 = ROT(x1, r); x1 ^= x0; }
    x0 += k0; x1 += k1;
    RND(13) RND(15) RND(26) RND(6)
    x0 += k1; x1 += k2 + 1u;
    RND(17) RND(29) RND(16) RND(24)
    x0 += k2; x1 += k0 + 2u;
    RND(13) RND(15) RND(26) RND(6)
    x0 += k0; x1 += k1 + 3u;
    RND(17) RND(29) RND(16) RND(24)
    x0 += k1; x1 += k2 + 4u;
    RND(13) RND(15) RND(26) RND(6)
    x0 += k2; x1 += k0 + 5u;
    y0 = x0; y1 = x1;
#undef RND
#undef ROT
}

// ---------------- points2img scatter + 2x downsample ----------------
__global__ void k_scatter(const float* __restrict__ pos, int* __restrict__ img)
{
    int t = blockIdx.x * 256 + threadIdx.x;
    int b = t / NPTS, n = t - b * NPTS;
    int x = (int)pos[(size_t)t * 2];
    int y = (int)pos[(size_t)t * 2 + 1];
    img[(size_t)b * NPTS + y * 112 + x] = n;
}

__global__ void k_down(const int* __restrict__ img, int* __restrict__ idxa)
{
    int q = blockIdx.x * 256 + threadIdx.x;
    int b = q / N2, p2 = q - b * N2;
    int r = p2 / 56, c = p2 - r * 56;
    idxa[q] = img[(size_t)b * NPTS + (2 * r) * 112 + 2 * c];
}

// ---------------- lin_W -> fp8 B-tiles: [kc 0..95][row n 0..383][64B], swizzled ----------------
__global__ __launch_bounds__(256) void k_linT(const float* __restrict__ W, uchar* __restrict__ T)
{
    __shared__ float tile[64][65];
    int q0 = blockIdx.x * 64, n0 = blockIdx.y * 64;
    for (int s = 0; s < 16; ++s) {
        int id = threadIdx.x + s * 256;
        int i = id >> 6, j = id & 63;
        int q = q0 + i;
        int w = q & 63;
        int kap = (q & ~63) + 8 * ((w >> 4) & 3) + 32 * ((w >> 3) & 1) + (w & 7);
        int c = kap >> 5, k = kap & 31;
        tile[i][j] = W[(size_t)(k * 192 + c) * 384 + n0 + j];
    }
    __syncthreads();
    for (int s = 0; s < 16; ++s) {
        int id = threadIdx.x + s * 256;
        int jj = id >> 6, ii = id & 63;
        int q = q0 + ii, n = n0 + jj;
        int gp = ((q >> 4) & 3) ^ ((n >> 1) & 3);
        T[(size_t)(q >> 6) * 24576 + n * 64 + gp * 16 + (q & 15)] = f2e4m3(tile[ii][jj]);
    }
}

// ---------------- precompute f1W MFMA B-fragments (bf16): frag[ks][w][lane][j] ----------------
__global__ __launch_bounds__(256) void k_prep(const float* __restrict__ f1W, ushort_t* __restrict__ frag)
{
    int t = blockIdx.x * 256 + threadIdx.x;   // 12288 total
    int j = t & 7;
    int lane = (t >> 3) & 63;
    int w = (t >> 9) & 3;
    int ks = t >> 11;
    int k = ks * 32 + (lane >> 4) * 8 + j;
    int o = w * 16 + (lane & 15);
    frag[t] = f2bf(f1W[k * 64 + o]);
}

// ---------------- per-point: ONE WAVE PER POINT, fused LayerNorm, no barriers ----------------
__global__ __launch_bounds__(256) void k_point(
    const float* __restrict__ pos, const float* __restrict__ feat,
    const float* __restrict__ maskp,
    const int* __restrict__ massign, const int* __restrict__ memidx,
    const float* __restrict__ cmaskp,
    const int* __restrict__ idxarr, const ushort_t* __restrict__ f1frag,
    const float* __restrict__ norm_g, const float* __restrict__ norm_b,
    const float* __restrict__ w1W, const float* __restrict__ w1b,
    const float* __restrict__ lng, const float* __restrict__ lnb,
    const float* __restrict__ f1b,
    const float* __restrict__ f2W, const float* __restrict__ f2b,
    uchar* __restrict__ agg, float* __restrict__ outbuf, int p0)
{
    __shared__ __align__(16) ushort_t frelb[4][4][200];
    __shared__ __align__(16) float wsm[4][4][32];
    __shared__ __align__(16) float hbuf[4][4][64];

    int tid = threadIdx.x;
    int wave = tid >> 6, lane = tid & 63;
    int l15 = lane & 15, l4 = lane >> 4;
    int point = p0 + blockIdx.x * 4 + wave;
    int b = point / N2;
    size_t browbase = (size_t)b * NPTS;
    int idx_pt = idxarr[point];

    // phase 1: scoring, 2 items per lane (items lane, lane+64)
    int j8 = lane >> 4, i16 = lane & 15;
    int maj_lo = massign[(browbase + idx_pt) * 8 + j8];
    int maj_hi = massign[(browbase + idx_pt) * 8 + 4 + j8];
    size_t roff_lo = ((size_t)b * KCL + maj_lo) * 16 + i16;
    size_t roff_hi = ((size_t)b * KCL + maj_hi) * 16 + i16;
    int mv_lo = memidx[roff_lo], mv_hi = memidx[roff_hi];
    float cv_lo = cmaskp[roff_lo]; if (mv_lo == idx_pt) cv_lo = 0.f;
    float cv_hi = cmaskp[roff_hi]; if (mv_hi == idx_pt) cv_hi = 0.f;
    float pr_lo = fmaxf(cv_lo, 1e-5f), pr_hi = fmaxf(cv_hi, 1e-5f);
    uint32 y0, y1;
    threefry(0u, (uint32)point * 128u + (uint32)lane, y0, y1);
    uint32 bits_lo = y0 ^ y1;
    threefry(0u, (uint32)point * 128u + (uint32)lane + 64u, y0, y1);
    uint32 bits_hi = y0 ^ y1;
    union { uint32 u; float f; } cu;
    cu.u = (bits_lo >> 9) | 0x3f800000u; float u_lo = cu.f - 1.0f;
    cu.u = (bits_hi >> 9) | 0x3f800000u; float u_hi = cu.f - 1.0f;
    float a0 = logf(pr_lo) - logf(-logf(u_lo + 1e-20f) + 1e-20f);
    float a1 = logf(pr_hi) - logf(-logf(u_hi + 1e-20f) + 1e-20f);

    float pdx = pos[(browbase + idx_pt) * 2];
    float pdy = pos[(browbase + idx_pt) * 2 + 1];
    if (lane == 0) {
        outbuf[OUT_MASK_OFF + point] = maskp[browbase + idx_pt];
        outbuf[(size_t)point * 2]     = floorf(pdx * 0.5f);
        outbuf[(size_t)point * 2 + 1] = floorf(pdy * 0.5f);
    }

    // phase 2: in-wave top-4 butterfly (ties -> lower index)
    float aa0 = a0, aa1 = a1;
    float tops[4]; int topi[4];
#pragma unroll
    for (int pass = 0; pass < 4; ++pass) {
        float s; int si;
        if (aa0 >= aa1) { s = aa0; si = lane; } else { s = aa1; si = lane + 64; }
#pragma unroll
        for (int d = 32; d >= 1; d >>= 1) {
            float s2 = __shfl_xor(s, d, 64);
            int i2 = __shfl_xor(si, d, 64);
            if (s2 > s || (s2 == s && i2 < si)) { s = s2; si = i2; }
        }
        tops[pass] = s; topi[pass] = si;
        if (si == lane) aa0 = -FNEG;
        if (si == lane + 64) aa1 = -FNEG;
    }
    int mc0 = (topi[0] < 64) ? __shfl(mv_lo, topi[0], 64) : __shfl(mv_hi, topi[0] - 64, 64);
    int mc1 = (topi[1] < 64) ? __shfl(mv_lo, topi[1], 64) : __shfl(mv_hi, topi[1] - 64, 64);
    int mc2 = (topi[2] < 64) ? __shfl(mv_lo, topi[2], 64) : __shfl(mv_hi, topi[2] - 64, 64);
    if (tops[2] - tops[3] < 1e-4f) {
        double b0 = log((double)pr_lo) - log(-log((double)u_lo + 1e-20) + 1e-20);
        double b1 = log((double)pr_hi) - log(-log((double)u_hi + 1e-20) + 1e-20);
        int mcs[3];
#pragma unroll
        for (int pass = 0; pass < 3; ++pass) {
            double s; int si;
            if (b0 >= b1) { s = b0; si = lane; } else { s = b1; si = lane + 64; }
            for (int d = 32; d >= 1; d >>= 1) {
                double s2 = __shfl_xor(s, d, 64);
                int i2 = __shfl_xor(si, d, 64);
                if (s2 > s || (s2 == s && i2 < si)) { s = s2; si = i2; }
            }
            mcs[pass] = (si < 64) ? __shfl(mv_lo, si, 64) : __shfl(mv_hi, si - 64, 64);
            if (si == lane) b0 = -1.0e300;
            if (si == lane + 64) b1 = -1.0e300;
        }
        mc0 = mcs[0]; mc1 = mcs[1]; mc2 = mcs[2];
    }
    int rows[4] = { mc0, mc1, mc2, idx_pt };

    // phase 3: gather raw feat rows + fused LayerNorm (in-wave reductions); prel
    float ng0 = norm_g[lane], ng1 = norm_g[lane + 64], ng2 = norm_g[lane + 128];
    float nb0 = norm_b[lane], nb1 = norm_b[lane + 64], nb2 = norm_b[lane + 128];
    float fgv[4][3];
    float prelx[4], prely[4];
#pragma unroll
    for (int m = 0; m < 4; ++m) {
        size_t rbase = (browbase + rows[m]) * (size_t)CC;
        float v0 = feat[rbase + lane];
        float v1 = feat[rbase + lane + 64];
        float v2 = feat[rbase + lane + 128];
        float s = v0 + v1 + v2;
#pragma unroll
        for (int d = 32; d >= 1; d >>= 1) s += __shfl_xor(s, d, 64);
        float mu = s * (1.f / 192.f);
        float d0 = v0 - mu, d1 = v1 - mu, d2 = v2 - mu;
        float q = d0 * d0 + d1 * d1 + d2 * d2;
#pragma unroll
        for (int d = 32; d >= 1; d >>= 1) q += __shfl_xor(q, d, 64);
        float rstd = 1.f / sqrtf(q * (1.f / 192.f) + 1e-5f);
        fgv[m][0] = d0 * rstd * ng0 + nb0;
        fgv[m][1] = d1 * rstd * ng1 + nb1;
        fgv[m][2] = d2 * rstd * ng2 + nb2;
        prelx[m] = pos[(browbase + rows[m]) * 2]     - pdx;
        prely[m] = pos[(browbase + rows[m]) * 2 + 1] - pdy;
    }

    // phase 4a: frelb build (this wave's private slice)
#pragma unroll
    for (int m = 0; m < 4; ++m)
#pragma unroll
        for (int jj = 0; jj < 3; ++jj)
            frelb[wave][m][lane + jj * 64] = f2bf(fgv[m][jj] - fgv[3][jj]);

    // phase 4b: pos MLP, 2 m-rows per lane
    {
        int kk = lane & 31;
        int mbase = lane >> 5;
#pragma unroll
        for (int t = 0; t < 2; ++t) {
            int m = mbase + 2 * t;
            float px = (m == 0) ? prelx[0] : (m == 1) ? prelx[1] : (m == 2) ? prelx[2] : prelx[3];
            float py = (m == 0) ? prely[0] : (m == 1) ? prely[1] : (m == 2) ? prely[2] : prely[3];
            float pre = px * w1W[kk] + py * w1W[32 + kk] + w1b[kk];
            float s = pre;
            for (int d = 16; d >= 1; d >>= 1) s += __shfl_xor(s, d, 64);
            float mu = s * (1.f / 32.f);
            float dv = pre - mu;
            float vs = dv * dv;
            for (int d = 16; d >= 1; d >>= 1) vs += __shfl_xor(vs, d, 64);
            float var = vs * (1.f / 32.f);
            float nv = dv / sqrtf(var + 1e-5f) * lng[kk] + lnb[kk];
            wsm[wave][m][kk] = gelu_fast(nv);
        }
    }

    // phase 5: gate MFMA — one wave does all 4 o-tiles (24 MFMAs)
    f32x4 acc[4];
#pragma unroll
    for (int w = 0; w < 4; ++w) acc[w] = (f32x4){0.f, 0.f, 0.f, 0.f};
#pragma unroll
    for (int ks = 0; ks < 6; ++ks) {
        short8 av;
        if (l15 < 4) av = *(const short8*)(&frelb[wave][l15][ks * 32 + l4 * 8]);
        else av = (short8){0,0,0,0,0,0,0,0};
#pragma unroll
        for (int w = 0; w < 4; ++w) {
            short8 bv = *(const short8*)(f1frag + ((size_t)(ks * 4 + w) * 64 + lane) * 8);
            acc[w] = __builtin_amdgcn_mfma_f32_16x16x32_bf16(av, bv, acc[w], 0, 0, 0);
        }
    }
    if (l4 == 0) {
#pragma unroll
        for (int w = 0; w < 4; ++w)
            *(f32x4*)(&hbuf[wave][w][l15 * 4]) = acc[w];
    }
    float fv = 0.f;
#pragma unroll
    for (int w = 0; w < 4; ++w) {
        float hv = hbuf[wave][w][lane];              // o = w*16 + (lane>>2), m = lane&3
        int o = w * 16 + (lane >> 2);
        fv += gelu_fast(hv + f1b[o]) * f2W[o];
    }
#pragma unroll
    for (int d = 4; d <= 32; d <<= 1) fv += __shfl_xor(fv, d, 64);
    fv = 1.f / (1.f + __expf(-(fv + f2b[0])));
    float fwv0 = __shfl(fv, (lane & ~3) | 0, 64);
    float fwv1 = __shfl(fv, (lane & ~3) | 1, 64);
    float fwv2 = __shfl(fv, (lane & ~3) | 2, 64);
    float fwv3 = __shfl(fv, (lane & ~3) | 3, 64);

    // phase 6: agg -> fp8 panels. lane owns c = lane + 64*i3; loop r (k = 8r..8r+7)
    {
        float g0[3], g1[3], g2[3], g3[3];
#pragma unroll
        for (int i3 = 0; i3 < 3; ++i3) {
            g0[i3] = fgv[0][i3] * fwv0;
            g1[i3] = fgv[1][i3] * fwv1;
            g2[i3] = fgv[2][i3] * fwv2;
            g3[i3] = fgv[3][i3] * fwv3;
        }
        int mrow = point & 127;
        uchar* ppan = agg + (size_t)(point >> 7) * PANEL + (size_t)mrow * 64;
#pragma unroll
        for (int r = 0; r < 4; ++r) {
            f32x4 wq0a = *(const f32x4*)(&wsm[wave][0][8 * r]);
            f32x4 wq0b = *(const f32x4*)(&wsm[wave][0][8 * r + 4]);
            f32x4 wq1a = *(const f32x4*)(&wsm[wave][1][8 * r]);
            f32x4 wq1b = *(const f32x4*)(&wsm[wave][1][8 * r + 4]);
            f32x4 wq2a = *(const f32x4*)(&wsm[wave][2][8 * r]);
            f32x4 wq2b = *(const f32x4*)(&wsm[wave][2][8 * r + 4]);
            f32x4 wq3a = *(const f32x4*)(&wsm[wave][3][8 * r]);
            f32x4 wq3b = *(const f32x4*)(&wsm[wave][3][8 * r + 4]);
            int gp = (r ^ ((mrow >> 1) & 3)) << 4;
#pragma unroll
            for (int i3 = 0; i3 < 3; ++i3) {
                int c = lane + 64 * i3;
                float v[8];
#pragma unroll
                for (int i = 0; i < 4; ++i) {
                    v[i]     = g0[i3] * wq0a[i] + g1[i3] * wq1a[i] + g2[i3] * wq2a[i] + g3[i3] * wq3a[i];
                    v[i + 4] = g0[i3] * wq0b[i] + g1[i3] * wq1b[i] + g2[i3] * wq2b[i] + g3[i3] * wq3b[i];
                }
                uint32 w0_ = __builtin_amdgcn_cvt_pk_fp8_f32(v[0], v[1], 0, false);
                w0_ = __builtin_amdgcn_cvt_pk_fp8_f32(v[2], v[3], w0_, true);
                uint32 w1_ = __builtin_amdgcn_cvt_pk_fp8_f32(v[4], v[5], 0, false);
                w1_ = __builtin_amdgcn_cvt_pk_fp8_f32(v[6], v[7], w1_, true);
                *(u32x2*)(ppan + (size_t)(c >> 1) * 8192 + gp + 8 * (c & 1)) = (u32x2){w0_, w1_};
            }
        }
    }
}

// ---- GEMM: MX-scaled fp8 (scale=1.0), 32x32x64, BN=384, pre-tiled panels, 4-buf depth-3 ----
__global__ __launch_bounds__(256, 1) void k_gemm(const uchar* __restrict__ A,
    const uchar* __restrict__ BT, const float* __restrict__ bias,
    float* __restrict__ out, int p0)
{
    __shared__ __align__(16) uchar lds[4][32768];   // per buf: A[128][64] @0, B[384][64] @8192
    int tid = threadIdx.x;
    int wave = tid >> 6, lane = tid & 63;
    int l31 = lane & 31, h = lane >> 5;
    int m0 = blockIdx.x * 128;

    const uchar* Apan = A + ((size_t)(p0 >> 7) + blockIdx.x) * PANEL;

    f32x16 acc[4][3];
#pragma unroll
    for (int a = 0; a < 4; ++a)
#pragma unroll
        for (int bb = 0; bb < 3; ++bb)
#pragma unroll
            for (int e = 0; e < 16; ++e) acc[a][bb][e] = 0.f;

    auto stage = [&](int buf, int t) {
        const uchar* as = Apan + (size_t)t * 8192 + tid * 16;
        const uchar* bs = BT + (size_t)t * 24576 + tid * 16;
        uchar* ld = &lds[buf][0] + tid * 16;
#pragma unroll
        for (int i = 0; i < 2; ++i) gld16(as + i * 4096, ld + i * 4096);
#pragma unroll
        for (int i = 0; i < 6; ++i) gld16(bs + i * 4096, ld + 8192 + i * 4096);
    };

    int fsw = (l31 >> 1) & 3;
    int g0 = ((2 * h) ^ fsw) * 16;
    int g1 = ((2 * h + 1) ^ fsw) * 16;
    auto compute = [&](int t) {
        const uchar* Ab = &lds[t & 3][0];
        const uchar* Bb = Ab + 8192;
        union V8 { i64x2 hh[2]; i32x8 v; };
        V8 av[4], bv[3];
#pragma unroll
        for (int a = 0; a < 4; ++a) {
            int ro = (32 * a + l31) * 64;
            av[a].hh[0] = *(const i64x2*)(Ab + ro + g0);
            av[a].hh[1] = *(const i64x2*)(Ab + ro + g1);
        }
#pragma unroll
        for (int bb = 0; bb < 3; ++bb) {
            int ro = (wave * 96 + 32 * bb + l31) * 64;
            bv[bb].hh[0] = *(const i64x2*)(Bb + ro + g0);
            bv[bb].hh[1] = *(const i64x2*)(Bb + ro + g1);
        }
#pragma unroll
        for (int a = 0; a < 4; ++a)
#pragma unroll
            for (int bb = 0; bb < 3; ++bb)
                acc[a][bb] = __builtin_amdgcn_mfma_scale_f32_32x32x64_f8f6f4(
                    av[a].v, bv[bb].v, acc[a][bb], 0, 0, 0, 0x7F, 0, 0x7F);
    };

    // depth-3 pipeline, 8 gld16/thread/stage -> vmcnt(16) drains the oldest stage
    stage(0, 0);
    stage(1, 1);
    stage(2, 2);
    for (int t = 0; t < 94; ++t) {
        asm volatile("s_waitcnt vmcnt(16)" ::: "memory");
        __builtin_amdgcn_s_barrier();
        __builtin_amdgcn_sched_barrier(0);
        if (t < 93) stage((t + 3) & 3, t + 3);
        compute(t);
    }
    asm volatile("s_waitcnt vmcnt(8)" ::: "memory");
    __builtin_amdgcn_s_barrier();
    __builtin_amdgcn_sched_barrier(0);
    compute(94);
    asm volatile("s_waitcnt vmcnt(0)" ::: "memory");
    __builtin_amdgcn_s_barrier();
    __builtin_amdgcn_sched_barrier(0);
    compute(95);

    // C layout (32x32): col = lane&31, row = (reg&3) + 8*(reg>>2) + 4*(lane>>5)
#pragma unroll
    for (int a = 0; a < 4; ++a)
#pragma unroll
        for (int bb = 0; bb < 3; ++bb)
#pragma unroll
            for (int reg = 0; reg < 16; ++reg) {
                int rowm = (reg & 3) + 8 * (reg >> 2) + 4 * h;
                int rr = m0 + 32 * a + rowm;
                int cc = wave * 96 + 32 * bb + l31;
                out[(size_t)(p0 + rr) * 384 + cc] = acc[a][bb][reg] + bias[cc];
            }
}

extern "C" void kernel_launch(void* const* d_in, const int* in_sizes, int n_in,
                              void* d_out, int out_size, void* d_ws, size_t ws_size,
                              hipStream_t stream)
{
    const float* pos      = (const float*)d_in[0];
    const float* feat     = (const float*)d_in[1];
    const float* maskp    = (const float*)d_in[2];
    const int*   massign  = (const int*)d_in[4];
    const int*   memidx   = (const int*)d_in[5];
    const float* cmaskp   = (const float*)d_in[9];
    const float* norm_g   = (const float*)d_in[10];
    const float* norm_b   = (const float*)d_in[11];
    const float* w1W      = (const float*)d_in[12];
    const float* w1b      = (const float*)d_in[13];
    const float* lng      = (const float*)d_in[14];
    const float* lnb      = (const float*)d_in[15];
    const float* f1W      = (const float*)d_in[16];
    const float* f1b      = (const float*)d_in[17];
    const float* f2W      = (const float*)d_in[18];
    const float* f2b      = (const float*)d_in[19];
    const float* linW     = (const float*)d_in[20];
    const float* linb     = (const float*)d_in[21];

    char* ws = (char*)d_ws;
    int* img         = (int*)(ws);                      //    401,408 B
    int* idxa        = (int*)(ws + 401408);             //    100,352 B
    uchar* linT      = (uchar*)(ws + 501760);           //  2,359,296 B (fp8, tiled)
    ushort_t* f1frag = (ushort_t*)(ws + 2861056);       //     24,576 B
    uchar* agg       = (uchar*)(ws + 2885632);          // up to 154,140,672 B (fp8, panels)

    size_t avail = ws_size > 2885632 ? ws_size - 2885632 : 0;
    long long slabM = (long long)(avail / 6144);
    slabM &= ~127LL;
    if (slabM > TOTPTS) slabM = TOTPTS;
    if (slabM < 128) slabM = 128;

    hipMemsetAsync(img, 0, 401408, stream);
    k_scatter<<<392, 256, 0, stream>>>(pos, img);
    k_down<<<98, 256, 0, stream>>>(img, idxa);
    k_linT<<<dim3(96, 6), 256, 0, stream>>>(linW, linT);
    k_prep<<<48, 256, 0, stream>>>(f1W, f1frag);

    float* outF = (float*)d_out;
    for (int p0 = 0; p0 < TOTPTS; p0 += (int)slabM) {
        int cnt = TOTPTS - p0; if (cnt > (int)slabM) cnt = (int)slabM;
        k_point<<<cnt / 4, 256, 0, stream>>>(pos, feat, maskp, massign, memidx, cmaskp, idxa, f1frag,
                norm_g, norm_b, w1W, w1b, lng, lnb, f1b, f2W, f2b, agg, outF, p0);
        k_gemm<<<cnt / 128, 256, 0, stream>>>(agg, linT, linb, outF + OUT_FEAT_OFF, p0);
    }
}

// Round 23
// 187.389 us; speedup vs baseline: 1.1523x; 1.0017x over previous
//
#include <hip/hip_runtime.h>

typedef unsigned short ushort_t;
typedef unsigned char uchar;
typedef unsigned int uint32;
typedef __attribute__((ext_vector_type(8))) short short8;
typedef __attribute__((ext_vector_type(4))) float f32x4;
typedef __attribute__((ext_vector_type(16))) float f32x16;
typedef __attribute__((ext_vector_type(2))) unsigned int u32x2;
typedef __attribute__((ext_vector_type(2))) long long i64x2;
typedef __attribute__((ext_vector_type(8))) int i32x8;

#define BATCH 8
#define NPTS 12544
#define CC 192
#define KCL 784
#define N2 3136
#define TOTPTS 25088        // BATCH*N2
#define OUT_FEAT_OFF 50176
#define OUT_MASK_OFF 9683968
#define FNEG 3.402823466e38f
#define PANEL 786432        // 128*6144 bytes per A panel

__device__ __forceinline__ ushort_t f2bf(float f) {
    union { float f; uint32 u; } v; v.f = f;
    uint32 u = v.u;
    uint32 r = (u + 0x7FFFu + ((u >> 16) & 1u)) >> 16;
    return (ushort_t)r;
}
// tanh-form gelu (|diff vs exact erf-gelu| <= ~3e-3; negligible vs fp8 path error)
__device__ __forceinline__ float gelu_fast(float x) {
    float y = 0.7978845608f * x * (1.f + 0.044715f * x * x);
    float e = __expf(2.f * y);
    float t = 1.f - 2.f / (e + 1.f);
    return 0.5f * x * (1.f + t);
}
__device__ __forceinline__ uchar f2e4m3(float f) {
    return (uchar)(__builtin_amdgcn_cvt_pk_fp8_f32(f, f, 0, false) & 0xFF);
}

__device__ __forceinline__ void gld16(const void* g, void* l) {
    __builtin_amdgcn_global_load_lds((const __attribute__((address_space(1))) void*)g,
                                     (__attribute__((address_space(3))) void*)l, 16, 0, 0);
}

// JAX threefry2x32 with key = (0, 42)
__device__ __forceinline__ void threefry(uint32 x0, uint32 x1, uint32& y0, uint32& y1) {
    const uint32 k0 = 0u, k1 = 42u;
    const uint32 k2 = 0u ^ 42u ^ 0x1BD11BDAu;
#define ROT(v,r) (((v) << (r)) | ((v) >> (32 - (r))))
#define RND(r) { x0 += x1; x1 = ROT(x1, r); x1 ^= x0; }
    x0 += k0; x1 += k1;
    RND(13) RND(15) RND(26) RND(6)
    x0 += k1; x1 += k2 + 1u;
    RND(17) RND(29) RND(16) RND(24)
    x0 += k2; x1 += k0 + 2u;
    RND(13) RND(15) RND(26) RND(6)
    x0 += k0; x1 += k1 + 3u;
    RND(17) RND(29) RND(16) RND(24)
    x0 += k1; x1 += k2 + 4u;
    RND(13) RND(15) RND(26) RND(6)
    x0 += k2; x1 += k0 + 5u;
    y0 = x0; y1 = x1;
#undef RND
#undef ROT
}

// ---------------- points2img scatter + 2x downsample ----------------
__global__ void k_scatter(const float* __restrict__ pos, int* __restrict__ img)
{
    int t = blockIdx.x * 256 + threadIdx.x;
    int b = t / NPTS, n = t - b * NPTS;
    int x = (int)pos[(size_t)t * 2];
    int y = (int)pos[(size_t)t * 2 + 1];
    img[(size_t)b * NPTS + y * 112 + x] = n;
}

__global__ void k_down(const int* __restrict__ img, int* __restrict__ idxa)
{
    int q = blockIdx.x * 256 + threadIdx.x;
    int b = q / N2, p2 = q - b * N2;
    int r = p2 / 56, c = p2 - r * 56;
    idxa[q] = img[(size_t)b * NPTS + (2 * r) * 112 + 2 * c];
}

// ---------------- lin_W -> fp8 B-tiles: [kc 0..95][row n 0..383][64B], swizzled ----------------
__global__ __launch_bounds__(256) void k_linT(const float* __restrict__ W, uchar* __restrict__ T)
{
    __shared__ float tile[64][65];
    int q0 = blockIdx.x * 64, n0 = blockIdx.y * 64;
    for (int s = 0; s < 16; ++s) {
        int id = threadIdx.x + s * 256;
        int i = id >> 6, j = id & 63;
        int q = q0 + i;
        int w = q & 63;
        int kap = (q & ~63) + 8 * ((w >> 4) & 3) + 32 * ((w >> 3) & 1) + (w & 7);
        int c = kap >> 5, k = kap & 31;
        tile[i][j] = W[(size_t)(k * 192 + c) * 384 + n0 + j];
    }
    __syncthreads();
    for (int s = 0; s < 16; ++s) {
        int id = threadIdx.x + s * 256;
        int jj = id >> 6, ii = id & 63;
        int q = q0 + ii, n = n0 + jj;
        int gp = ((q >> 4) & 3) ^ ((n >> 1) & 3);
        T[(size_t)(q >> 6) * 24576 + n * 64 + gp * 16 + (q & 15)] = f2e4m3(tile[ii][jj]);
    }
}

// ---------------- precompute f1W MFMA B-fragments (bf16): frag[ks][w][lane][j] ----------------
__global__ __launch_bounds__(256) void k_prep(const float* __restrict__ f1W, ushort_t* __restrict__ frag)
{
    int t = blockIdx.x * 256 + threadIdx.x;   // 12288 total
    int j = t & 7;
    int lane = (t >> 3) & 63;
    int w = (t >> 9) & 3;
    int ks = t >> 11;
    int k = ks * 32 + (lane >> 4) * 8 + j;
    int o = w * 16 + (lane & 15);
    frag[t] = f2bf(f1W[k * 64 + o]);
}

// ---------------- per-point: ONE WAVE PER POINT, fused LayerNorm, no barriers ----------------
__global__ __launch_bounds__(256) void k_point(
    const float* __restrict__ pos, const float* __restrict__ feat,
    const float* __restrict__ maskp,
    const int* __restrict__ massign, const int* __restrict__ memidx,
    const float* __restrict__ cmaskp,
    const int* __restrict__ idxarr, const ushort_t* __restrict__ f1frag,
    const float* __restrict__ norm_g, const float* __restrict__ norm_b,
    const float* __restrict__ w1W, const float* __restrict__ w1b,
    const float* __restrict__ lng, const float* __restrict__ lnb,
    const float* __restrict__ f1b,
    const float* __restrict__ f2W, const float* __restrict__ f2b,
    uchar* __restrict__ agg, float* __restrict__ outbuf, int p0)
{
    __shared__ __align__(16) ushort_t frelb[4][4][200];
    __shared__ __align__(16) float wsm[4][4][32];
    __shared__ __align__(16) float hbuf[4][4][64];

    int tid = threadIdx.x;
    int wave = tid >> 6, lane = tid & 63;
    int l15 = lane & 15, l4 = lane >> 4;
    int point = p0 + blockIdx.x * 4 + wave;
    int b = point / N2;
    size_t browbase = (size_t)b * NPTS;
    int idx_pt = idxarr[point];

    // phase 1: scoring, 2 items per lane (items lane, lane+64)
    int j8 = lane >> 4, i16 = lane & 15;
    int maj_lo = massign[(browbase + idx_pt) * 8 + j8];
    int maj_hi = massign[(browbase + idx_pt) * 8 + 4 + j8];
    size_t roff_lo = ((size_t)b * KCL + maj_lo) * 16 + i16;
    size_t roff_hi = ((size_t)b * KCL + maj_hi) * 16 + i16;
    int mv_lo = memidx[roff_lo], mv_hi = memidx[roff_hi];
    float cv_lo = cmaskp[roff_lo]; if (mv_lo == idx_pt) cv_lo = 0.f;
    float cv_hi = cmaskp[roff_hi]; if (mv_hi == idx_pt) cv_hi = 0.f;
    float pr_lo = fmaxf(cv_lo, 1e-5f), pr_hi = fmaxf(cv_hi, 1e-5f);
    uint32 y0, y1;
    threefry(0u, (uint32)point * 128u + (uint32)lane, y0, y1);
    uint32 bits_lo = y0 ^ y1;
    threefry(0u, (uint32)point * 128u + (uint32)lane + 64u, y0, y1);
    uint32 bits_hi = y0 ^ y1;
    union { uint32 u; float f; } cu;
    cu.u = (bits_lo >> 9) | 0x3f800000u; float u_lo = cu.f - 1.0f;
    cu.u = (bits_hi >> 9) | 0x3f800000u; float u_hi = cu.f - 1.0f;
    float a0 = logf(pr_lo) - logf(-logf(u_lo + 1e-20f) + 1e-20f);
    float a1 = logf(pr_hi) - logf(-logf(u_hi + 1e-20f) + 1e-20f);

    float pdx = pos[(browbase + idx_pt) * 2];
    float pdy = pos[(browbase + idx_pt) * 2 + 1];
    if (lane == 0) {
        outbuf[OUT_MASK_OFF + point] = maskp[browbase + idx_pt];
        outbuf[(size_t)point * 2]     = floorf(pdx * 0.5f);
        outbuf[(size_t)point * 2 + 1] = floorf(pdy * 0.5f);
    }

    // phase 2: in-wave top-4 butterfly (ties -> lower index)
    float aa0 = a0, aa1 = a1;
    float tops[4]; int topi[4];
#pragma unroll
    for (int pass = 0; pass < 4; ++pass) {
        float s; int si;
        if (aa0 >= aa1) { s = aa0; si = lane; } else { s = aa1; si = lane + 64; }
#pragma unroll
        for (int d = 32; d >= 1; d >>= 1) {
            float s2 = __shfl_xor(s, d, 64);
            int i2 = __shfl_xor(si, d, 64);
            if (s2 > s || (s2 == s && i2 < si)) { s = s2; si = i2; }
        }
        tops[pass] = s; topi[pass] = si;
        if (si == lane) aa0 = -FNEG;
        if (si == lane + 64) aa1 = -FNEG;
    }
    int mc0 = (topi[0] < 64) ? __shfl(mv_lo, topi[0], 64) : __shfl(mv_hi, topi[0] - 64, 64);
    int mc1 = (topi[1] < 64) ? __shfl(mv_lo, topi[1], 64) : __shfl(mv_hi, topi[1] - 64, 64);
    int mc2 = (topi[2] < 64) ? __shfl(mv_lo, topi[2], 64) : __shfl(mv_hi, topi[2] - 64, 64);
    if (tops[2] - tops[3] < 1e-4f) {
        double b0 = log((double)pr_lo) - log(-log((double)u_lo + 1e-20) + 1e-20);
        double b1 = log((double)pr_hi) - log(-log((double)u_hi + 1e-20) + 1e-20);
        int mcs[3];
#pragma unroll
        for (int pass = 0; pass < 3; ++pass) {
            double s; int si;
            if (b0 >= b1) { s = b0; si = lane; } else { s = b1; si = lane + 64; }
            for (int d = 32; d >= 1; d >>= 1) {
                double s2 = __shfl_xor(s, d, 64);
                int i2 = __shfl_xor(si, d, 64);
                if (s2 > s || (s2 == s && i2 < si)) { s = s2; si = i2; }
            }
            mcs[pass] = (si < 64) ? __shfl(mv_lo, si, 64) : __shfl(mv_hi, si - 64, 64);
            if (si == lane) b0 = -1.0e300;
            if (si == lane + 64) b1 = -1.0e300;
        }
        mc0 = mcs[0]; mc1 = mcs[1]; mc2 = mcs[2];
    }
    int rows[4] = { mc0, mc1, mc2, idx_pt };

    // phase 3: gather raw feat rows + fused LayerNorm (in-wave reductions); prel
    float ng0 = norm_g[lane], ng1 = norm_g[lane + 64], ng2 = norm_g[lane + 128];
    float nb0 = norm_b[lane], nb1 = norm_b[lane + 64], nb2 = norm_b[lane + 128];
    float fgv[4][3];
    float prelx[4], prely[4];
#pragma unroll
    for (int m = 0; m < 4; ++m) {
        size_t rbase = (browbase + rows[m]) * (size_t)CC;
        float v0 = feat[rbase + lane];
        float v1 = feat[rbase + lane + 64];
        float v2 = feat[rbase + lane + 128];
        float s = v0 + v1 + v2;
#pragma unroll
        for (int d = 32; d >= 1; d >>= 1) s += __shfl_xor(s, d, 64);
        float mu = s * (1.f / 192.f);
        float d0 = v0 - mu, d1 = v1 - mu, d2 = v2 - mu;
        float q = d0 * d0 + d1 * d1 + d2 * d2;
#pragma unroll
        for (int d = 32; d >= 1; d >>= 1) q += __shfl_xor(q, d, 64);
        float rstd = 1.f / sqrtf(q * (1.f / 192.f) + 1e-5f);
        fgv[m][0] = d0 * rstd * ng0 + nb0;
        fgv[m][1] = d1 * rstd * ng1 + nb1;
        fgv[m][2] = d2 * rstd * ng2 + nb2;
        prelx[m] = pos[(browbase + rows[m]) * 2]     - pdx;
        prely[m] = pos[(browbase + rows[m]) * 2 + 1] - pdy;
    }

    // phase 4a: frelb build (this wave's private slice)
#pragma unroll
    for (int m = 0; m < 4; ++m)
#pragma unroll
        for (int jj = 0; jj < 3; ++jj)
            frelb[wave][m][lane + jj * 64] = f2bf(fgv[m][jj] - fgv[3][jj]);

    // phase 4b: pos MLP, 2 m-rows per lane
    {
        int kk = lane & 31;
        int mbase = lane >> 5;
#pragma unroll
        for (int t = 0; t < 2; ++t) {
            int m = mbase + 2 * t;
            float px = (m == 0) ? prelx[0] : (m == 1) ? prelx[1] : (m == 2) ? prelx[2] : prelx[3];
            float py = (m == 0) ? prely[0] : (m == 1) ? prely[1] : (m == 2) ? prely[2] : prely[3];
            float pre = px * w1W[kk] + py * w1W[32 + kk] + w1b[kk];
            float s = pre;
            for (int d = 16; d >= 1; d >>= 1) s += __shfl_xor(s, d, 64);
            float mu = s * (1.f / 32.f);
            float dv = pre - mu;
            float vs = dv * dv;
            for (int d = 16; d >= 1; d >>= 1) vs += __shfl_xor(vs, d, 64);
            float var = vs * (1.f / 32.f);
            float nv = dv / sqrtf(var + 1e-5f) * lng[kk] + lnb[kk];
            wsm[wave][m][kk] = gelu_fast(nv);
        }
    }

    // phase 5: gate MFMA — one wave does all 4 o-tiles (24 MFMAs)
    f32x4 acc[4];
#pragma unroll
    for (int w = 0; w < 4; ++w) acc[w] = (f32x4){0.f, 0.f, 0.f, 0.f};
#pragma unroll
    for (int ks = 0; ks < 6; ++ks) {
        short8 av;
        if (l15 < 4) av = *(const short8*)(&frelb[wave][l15][ks * 32 + l4 * 8]);
        else av = (short8){0,0,0,0,0,0,0,0};
#pragma unroll
        for (int w = 0; w < 4; ++w) {
            short8 bv = *(const short8*)(f1frag + ((size_t)(ks * 4 + w) * 64 + lane) * 8);
            acc[w] = __builtin_amdgcn_mfma_f32_16x16x32_bf16(av, bv, acc[w], 0, 0, 0);
        }
    }
    if (l4 == 0) {
#pragma unroll
        for (int w = 0; w < 4; ++w)
            *(f32x4*)(&hbuf[wave][w][l15 * 4]) = acc[w];
    }
    float fv = 0.f;
#pragma unroll
    for (int w = 0; w < 4; ++w) {
        float hv = hbuf[wave][w][lane];              // o = w*16 + (lane>>2), m = lane&3
        int o = w * 16 + (lane >> 2);
        fv += gelu_fast(hv + f1b[o]) * f2W[o];
    }
#pragma unroll
    for (int d = 4; d <= 32; d <<= 1) fv += __shfl_xor(fv, d, 64);
    fv = 1.f / (1.f + __expf(-(fv + f2b[0])));
    float fwv0 = __shfl(fv, (lane & ~3) | 0, 64);
    float fwv1 = __shfl(fv, (lane & ~3) | 1, 64);
    float fwv2 = __shfl(fv, (lane & ~3) | 2, 64);
    float fwv3 = __shfl(fv, (lane & ~3) | 3, 64);

    // phase 6: agg -> fp8 panels. lane owns c = lane + 64*i3; loop r (k = 8r..8r+7)
    // inner contraction as f32x4 vector math -> v_pk_fma_f32 (2 FMA/instr)
    {
        float g0[3], g1[3], g2[3], g3[3];
#pragma unroll
        for (int i3 = 0; i3 < 3; ++i3) {
            g0[i3] = fgv[0][i3] * fwv0;
            g1[i3] = fgv[1][i3] * fwv1;
            g2[i3] = fgv[2][i3] * fwv2;
            g3[i3] = fgv[3][i3] * fwv3;
        }
        int mrow = point & 127;
        uchar* ppan = agg + (size_t)(point >> 7) * PANEL + (size_t)mrow * 64;
#pragma unroll
        for (int r = 0; r < 4; ++r) {
            f32x4 wq0a = *(const f32x4*)(&wsm[wave][0][8 * r]);
            f32x4 wq0b = *(const f32x4*)(&wsm[wave][0][8 * r + 4]);
            f32x4 wq1a = *(const f32x4*)(&wsm[wave][1][8 * r]);
            f32x4 wq1b = *(const f32x4*)(&wsm[wave][1][8 * r + 4]);
            f32x4 wq2a = *(const f32x4*)(&wsm[wave][2][8 * r]);
            f32x4 wq2b = *(const f32x4*)(&wsm[wave][2][8 * r + 4]);
            f32x4 wq3a = *(const f32x4*)(&wsm[wave][3][8 * r]);
            f32x4 wq3b = *(const f32x4*)(&wsm[wave][3][8 * r + 4]);
            int gp = (r ^ ((mrow >> 1) & 3)) << 4;
#pragma unroll
            for (int i3 = 0; i3 < 3; ++i3) {
                int c = lane + 64 * i3;
                f32x4 va = wq0a * g0[i3];
                va += wq1a * g1[i3];
                va += wq2a * g2[i3];
                va += wq3a * g3[i3];
                f32x4 vb = wq0b * g0[i3];
                vb += wq1b * g1[i3];
                vb += wq2b * g2[i3];
                vb += wq3b * g3[i3];
                uint32 w0_ = __builtin_amdgcn_cvt_pk_fp8_f32(va[0], va[1], 0, false);
                w0_ = __builtin_amdgcn_cvt_pk_fp8_f32(va[2], va[3], w0_, true);
                uint32 w1_ = __builtin_amdgcn_cvt_pk_fp8_f32(vb[0], vb[1], 0, false);
                w1_ = __builtin_amdgcn_cvt_pk_fp8_f32(vb[2], vb[3], w1_, true);
                *(u32x2*)(ppan + (size_t)(c >> 1) * 8192 + gp + 8 * (c & 1)) = (u32x2){w0_, w1_};
            }
        }
    }
}

// ---- GEMM: MX-scaled fp8 (scale=1.0), 32x32x64, BN=384, pre-tiled panels, 4-buf depth-3 ----
__global__ __launch_bounds__(256, 1) void k_gemm(const uchar* __restrict__ A,
    const uchar* __restrict__ BT, const float* __restrict__ bias,
    float* __restrict__ out, int p0)
{
    __shared__ __align__(16) uchar lds[4][32768];   // per buf: A[128][64] @0, B[384][64] @8192
    int tid = threadIdx.x;
    int wave = tid >> 6, lane = tid & 63;
    int l31 = lane & 31, h = lane >> 5;
    int m0 = blockIdx.x * 128;

    const uchar* Apan = A + ((size_t)(p0 >> 7) + blockIdx.x) * PANEL;

    f32x16 acc[4][3];
#pragma unroll
    for (int a = 0; a < 4; ++a)
#pragma unroll
        for (int bb = 0; bb < 3; ++bb)
#pragma unroll
            for (int e = 0; e < 16; ++e) acc[a][bb][e] = 0.f;

    auto stage = [&](int buf, int t) {
        const uchar* as = Apan + (size_t)t * 8192 + tid * 16;
        const uchar* bs = BT + (size_t)t * 24576 + tid * 16;
        uchar* ld = &lds[buf][0] + tid * 16;
#pragma unroll
        for (int i = 0; i < 2; ++i) gld16(as + i * 4096, ld + i * 4096);
#pragma unroll
        for (int i = 0; i < 6; ++i) gld16(bs + i * 4096, ld + 8192 + i * 4096);
    };

    int fsw = (l31 >> 1) & 3;
    int g0 = ((2 * h) ^ fsw) * 16;
    int g1 = ((2 * h + 1) ^ fsw) * 16;
    auto compute = [&](int t) {
        const uchar* Ab = &lds[t & 3][0];
        const uchar* Bb = Ab + 8192;
        union V8 { i64x2 hh[2]; i32x8 v; };
        V8 av[4], bv[3];
#pragma unroll
        for (int a = 0; a < 4; ++a) {
            int ro = (32 * a + l31) * 64;
            av[a].hh[0] = *(const i64x2*)(Ab + ro + g0);
            av[a].hh[1] = *(const i64x2*)(Ab + ro + g1);
        }
#pragma unroll
        for (int bb = 0; bb < 3; ++bb) {
            int ro = (wave * 96 + 32 * bb + l31) * 64;
            bv[bb].hh[0] = *(const i64x2*)(Bb + ro + g0);
            bv[bb].hh[1] = *(const i64x2*)(Bb + ro + g1);
        }
#pragma unroll
        for (int a = 0; a < 4; ++a)
#pragma unroll
            for (int bb = 0; bb < 3; ++bb)
                acc[a][bb] = __builtin_amdgcn_mfma_scale_f32_32x32x64_f8f6f4(
                    av[a].v, bv[bb].v, acc[a][bb], 0, 0, 0, 0x7F, 0, 0x7F);
    };

    // depth-3 pipeline, 8 gld16/thread/stage -> vmcnt(16) drains the oldest stage
    stage(0, 0);
    stage(1, 1);
    stage(2, 2);
    for (int t = 0; t < 94; ++t) {
        asm volatile("s_waitcnt vmcnt(16)" ::: "memory");
        __builtin_amdgcn_s_barrier();
        __builtin_amdgcn_sched_barrier(0);
        if (t < 93) stage((t + 3) & 3, t + 3);
        compute(t);
    }
    asm volatile("s_waitcnt vmcnt(8)" ::: "memory");
    __builtin_amdgcn_s_barrier();
    __builtin_amdgcn_sched_barrier(0);
    compute(94);
    asm volatile("s_waitcnt vmcnt(0)" ::: "memory");
    __builtin_amdgcn_s_barrier();
    __builtin_amdgcn_sched_barrier(0);
    compute(95);

    // C layout (32x32): col = lane&31, row = (reg&3) + 8*(reg>>2) + 4*(lane>>5)
#pragma unroll
    for (int a = 0; a < 4; ++a)
#pragma unroll
        for (int bb = 0; bb < 3; ++bb)
#pragma unroll
            for (int reg = 0; reg < 16; ++reg) {
                int rowm = (reg & 3) + 8 * (reg >> 2) + 4 * h;
                int rr = m0 + 32 * a + rowm;
                int cc = wave * 96 + 32 * bb + l31;
                out[(size_t)(p0 + rr) * 384 + cc] = acc[a][bb][reg] + bias[cc];
            }
}

extern "C" void kernel_launch(void* const* d_in, const int* in_sizes, int n_in,
                              void* d_out, int out_size, void* d_ws, size_t ws_size,
                              hipStream_t stream)
{
    const float* pos      = (const float*)d_in[0];
    const float* feat     = (const float*)d_in[1];
    const float* maskp    = (const float*)d_in[2];
    const int*   massign  = (const int*)d_in[4];
    const int*   memidx   = (const int*)d_in[5];
    const float* cmaskp   = (const float*)d_in[9];
    const float* norm_g   = (const float*)d_in[10];
    const float* norm_b   = (const float*)d_in[11];
    const float* w1W      = (const float*)d_in[12];
    const float* w1b      = (const float*)d_in[13];
    const float* lng      = (const float*)d_in[14];
    const float* lnb      = (const float*)d_in[15];
    const float* f1W      = (const float*)d_in[16];
    const float* f1b      = (const float*)d_in[17];
    const float* f2W      = (const float*)d_in[18];
    const float* f2b      = (const float*)d_in[19];
    const float* linW     = (const float*)d_in[20];
    const float* linb     = (const float*)d_in[21];

    char* ws = (char*)d_ws;
    int* img         = (int*)(ws);                      //    401,408 B
    int* idxa        = (int*)(ws + 401408);             //    100,352 B
    uchar* linT      = (uchar*)(ws + 501760);           //  2,359,296 B (fp8, tiled)
    ushort_t* f1frag = (ushort_t*)(ws + 2861056);       //     24,576 B
    uchar* agg       = (uchar*)(ws + 2885632);          // up to 154,140,672 B (fp8, panels)

    size_t avail = ws_size > 2885632 ? ws_size - 2885632 : 0;
    long long slabM = (long long)(avail / 6144);
    slabM &= ~127LL;
    if (slabM > TOTPTS) slabM = TOTPTS;
    if (slabM < 128) slabM = 128;

    hipMemsetAsync(img, 0, 401408, stream);
    k_scatter<<<392, 256, 0, stream>>>(pos, img);
    k_down<<<98, 256, 0, stream>>>(img, idxa);
    k_linT<<<dim3(96, 6), 256, 0, stream>>>(linW, linT);
    k_prep<<<48, 256, 0, stream>>>(f1W, f1frag);

    float* outF = (float*)d_out;
    for (int p0 = 0; p0 < TOTPTS; p0 += (int)slabM) {
        int cnt = TOTPTS - p0; if (cnt > (int)slabM) cnt = (int)slabM;
        k_point<<<cnt / 4, 256, 0, stream>>>(pos, feat, maskp, massign, memidx, cmaskp, idxa, f1frag,
                norm_g, norm_b, w1W, w1b, lng, lnb, f1b, f2W, f2b, agg, outF, p0);
        k_gemm<<<cnt / 128, 256, 0, stream>>>(agg, linT, linb, outF + OUT_FEAT_OFF, p0);
    }
}

// Round 24
// 183.138 us; speedup vs baseline: 1.1791x; 1.0232x over previous
//
#include <hip/hip_runtime.h>

typedef unsigned short ushort_t;
typedef unsigned char uchar;
typedef unsigned int uint32;
typedef __attribute__((ext_vector_type(8))) short short8;
typedef __attribute__((ext_vector_type(4))) float f32x4;
typedef __attribute__((ext_vector_type(16))) float f32x16;
typedef __attribute__((ext_vector_type(2))) unsigned int u32x2;
typedef __attribute__((ext_vector_type(2))) long long i64x2;
typedef __attribute__((ext_vector_type(8))) int i32x8;

#define BATCH 8
#define NPTS 12544
#define CC 192
#define KCL 784
#define N2 3136
#define TOTPTS 25088        // BATCH*N2
#define OUT_FEAT_OFF 50176
#define OUT_MASK_OFF 9683968
#define FNEG 3.402823466e38f
#define PANEL 786432        // 128*6144 bytes per A panel

__device__ __forceinline__ ushort_t f2bf(float f) {
    union { float f; uint32 u; } v; v.f = f;
    uint32 u = v.u;
    uint32 r = (u + 0x7FFFu + ((u >> 16) & 1u)) >> 16;
    return (ushort_t)r;
}
// tanh-form gelu (|diff vs exact erf-gelu| <= ~3e-3; negligible vs fp8 path error)
__device__ __forceinline__ float gelu_fast(float x) {
    float y = 0.7978845608f * x * (1.f + 0.044715f * x * x);
    float e = __expf(2.f * y);
    float t = 1.f - 2.f / (e + 1.f);
    return 0.5f * x * (1.f + t);
}
__device__ __forceinline__ uchar f2e4m3(float f) {
    return (uchar)(__builtin_amdgcn_cvt_pk_fp8_f32(f, f, 0, false) & 0xFF);
}

__device__ __forceinline__ void gld16(const void* g, void* l) {
    __builtin_amdgcn_global_load_lds((const __attribute__((address_space(1))) void*)g,
                                     (__attribute__((address_space(3))) void*)l, 16, 0, 0);
}

// JAX threefry2x32 with key = (0, 42)
__device__ __forceinline__ void threefry(uint32 x0, uint32 x1, uint32& y0, uint32& y1) {
    const uint32 k0 = 0u, k1 = 42u;
    const uint32 k2 = 0u ^ 42u ^ 0x1BD11BDAu;
#define ROT(v,r) (((v) << (r)) | ((v) >> (32 - (r))))
#define RND(r) { x0 += x1; x1 = ROT(x1, r); x1 ^= x0; }
    x0 += k0; x1 += k1;
    RND(13) RND(15) RND(26) RND(6)
    x0 += k1; x1 += k2 + 1u;
    RND(17) RND(29) RND(16) RND(24)
    x0 += k2; x1 += k0 + 2u;
    RND(13) RND(15) RND(26) RND(6)
    x0 += k0; x1 += k1 + 3u;
    RND(17) RND(29) RND(16) RND(24)
    x0 += k1; x1 += k2 + 4u;
    RND(13) RND(15) RND(26) RND(6)
    x0 += k2; x1 += k0 + 5u;
    y0 = x0; y1 = x1;
#undef RND
#undef ROT
}

// ---------------- points2img scatter + 2x downsample ----------------
__global__ void k_scatter(const float* __restrict__ pos, int* __restrict__ img)
{
    int t = blockIdx.x * 256 + threadIdx.x;
    int b = t / NPTS, n = t - b * NPTS;
    int x = (int)pos[(size_t)t * 2];
    int y = (int)pos[(size_t)t * 2 + 1];
    img[(size_t)b * NPTS + y * 112 + x] = n;
}

__global__ void k_down(const int* __restrict__ img, int* __restrict__ idxa)
{
    int q = blockIdx.x * 256 + threadIdx.x;
    int b = q / N2, p2 = q - b * N2;
    int r = p2 / 56, c = p2 - r * 56;
    idxa[q] = img[(size_t)b * NPTS + (2 * r) * 112 + 2 * c];
}

// ---------------- lin_W -> fp8 B-tiles: [kc 0..95][row n 0..383][64B], swizzled ----------------
__global__ __launch_bounds__(256) void k_linT(const float* __restrict__ W, uchar* __restrict__ T)
{
    __shared__ float tile[64][65];
    int q0 = blockIdx.x * 64, n0 = blockIdx.y * 64;
    for (int s = 0; s < 16; ++s) {
        int id = threadIdx.x + s * 256;
        int i = id >> 6, j = id & 63;
        int q = q0 + i;
        int w = q & 63;
        int kap = (q & ~63) + 8 * ((w >> 4) & 3) + 32 * ((w >> 3) & 1) + (w & 7);
        int c = kap >> 5, k = kap & 31;
        tile[i][j] = W[(size_t)(k * 192 + c) * 384 + n0 + j];
    }
    __syncthreads();
    for (int s = 0; s < 16; ++s) {
        int id = threadIdx.x + s * 256;
        int jj = id >> 6, ii = id & 63;
        int q = q0 + ii, n = n0 + jj;
        int gp = ((q >> 4) & 3) ^ ((n >> 1) & 3);
        T[(size_t)(q >> 6) * 24576 + n * 64 + gp * 16 + (q & 15)] = f2e4m3(tile[ii][jj]);
    }
}

// ---------------- precompute f1W MFMA B-fragments (bf16): frag[ks][w][lane][j] ----------------
__global__ __launch_bounds__(256) void k_prep(const float* __restrict__ f1W, ushort_t* __restrict__ frag)
{
    int t = blockIdx.x * 256 + threadIdx.x;   // 12288 total
    int j = t & 7;
    int lane = (t >> 3) & 63;
    int w = (t >> 9) & 3;
    int ks = t >> 11;
    int k = ks * 32 + (lane >> 4) * 8 + j;
    int o = w * 16 + (lane & 15);
    frag[t] = f2bf(f1W[k * 64 + o]);
}

// ---------------- per-point: ONE WAVE PER POINT, fused LayerNorm, latency-hoisted ----------------
__global__ __launch_bounds__(256) void k_point(
    const float* __restrict__ pos, const float* __restrict__ feat,
    const float* __restrict__ maskp,
    const int* __restrict__ massign, const int* __restrict__ memidx,
    const float* __restrict__ cmaskp,
    const int* __restrict__ idxarr, const ushort_t* __restrict__ f1frag,
    const float* __restrict__ norm_g, const float* __restrict__ norm_b,
    const float* __restrict__ w1W, const float* __restrict__ w1b,
    const float* __restrict__ lng, const float* __restrict__ lnb,
    const float* __restrict__ f1b,
    const float* __restrict__ f2W, const float* __restrict__ f2b,
    uchar* __restrict__ agg, float* __restrict__ outbuf, int p0)
{
    __shared__ __align__(16) ushort_t frelb[4][4][200];
    __shared__ __align__(16) float wsm[4][4][32];
    __shared__ __align__(16) float hbuf[4][4][64];

    int tid = threadIdx.x;
    int wave = tid >> 6, lane = tid & 63;
    int l15 = lane & 15, l4 = lane >> 4;
    int point = p0 + blockIdx.x * 4 + wave;
    int b = point / N2;
    size_t browbase = (size_t)b * NPTS;
    int idx_pt = idxarr[point];

    // EARLY: hoist row-3 (idx_pt) gather — overlaps threefry/log/argmax latency
    size_t rbase3 = (browbase + idx_pt) * (size_t)CC;
    float w30 = feat[rbase3 + lane];
    float w31 = feat[rbase3 + lane + 64];
    float w32 = feat[rbase3 + lane + 128];
    float pdx = pos[(browbase + idx_pt) * 2];
    float pdy = pos[(browbase + idx_pt) * 2 + 1];

    // phase 1: scoring, 2 items per lane (items lane, lane+64)
    int j8 = lane >> 4, i16 = lane & 15;
    int maj_lo = massign[(browbase + idx_pt) * 8 + j8];
    int maj_hi = massign[(browbase + idx_pt) * 8 + 4 + j8];
    size_t roff_lo = ((size_t)b * KCL + maj_lo) * 16 + i16;
    size_t roff_hi = ((size_t)b * KCL + maj_hi) * 16 + i16;
    int mv_lo = memidx[roff_lo], mv_hi = memidx[roff_hi];
    float cv_lo = cmaskp[roff_lo]; if (mv_lo == idx_pt) cv_lo = 0.f;
    float cv_hi = cmaskp[roff_hi]; if (mv_hi == idx_pt) cv_hi = 0.f;
    float pr_lo = fmaxf(cv_lo, 1e-5f), pr_hi = fmaxf(cv_hi, 1e-5f);
    uint32 y0, y1;
    threefry(0u, (uint32)point * 128u + (uint32)lane, y0, y1);
    uint32 bits_lo = y0 ^ y1;
    threefry(0u, (uint32)point * 128u + (uint32)lane + 64u, y0, y1);
    uint32 bits_hi = y0 ^ y1;
    union { uint32 u; float f; } cu;
    cu.u = (bits_lo >> 9) | 0x3f800000u; float u_lo = cu.f - 1.0f;
    cu.u = (bits_hi >> 9) | 0x3f800000u; float u_hi = cu.f - 1.0f;
    float a0 = logf(pr_lo) - logf(-logf(u_lo + 1e-20f) + 1e-20f);
    float a1 = logf(pr_hi) - logf(-logf(u_hi + 1e-20f) + 1e-20f);

    if (lane == 0) {
        outbuf[OUT_MASK_OFF + point] = maskp[browbase + idx_pt];
        outbuf[(size_t)point * 2]     = floorf(pdx * 0.5f);
        outbuf[(size_t)point * 2 + 1] = floorf(pdy * 0.5f);
    }

    // phase 2: in-wave top-4 butterfly (ties -> lower index)
    float aa0 = a0, aa1 = a1;
    float tops[4]; int topi[4];
#pragma unroll
    for (int pass = 0; pass < 4; ++pass) {
        float s; int si;
        if (aa0 >= aa1) { s = aa0; si = lane; } else { s = aa1; si = lane + 64; }
#pragma unroll
        for (int d = 32; d >= 1; d >>= 1) {
            float s2 = __shfl_xor(s, d, 64);
            int i2 = __shfl_xor(si, d, 64);
            if (s2 > s || (s2 == s && i2 < si)) { s = s2; si = i2; }
        }
        tops[pass] = s; topi[pass] = si;
        if (si == lane) aa0 = -FNEG;
        if (si == lane + 64) aa1 = -FNEG;
    }
    int mc0 = (topi[0] < 64) ? __shfl(mv_lo, topi[0], 64) : __shfl(mv_hi, topi[0] - 64, 64);
    int mc1 = (topi[1] < 64) ? __shfl(mv_lo, topi[1], 64) : __shfl(mv_hi, topi[1] - 64, 64);
    int mc2 = (topi[2] < 64) ? __shfl(mv_lo, topi[2], 64) : __shfl(mv_hi, topi[2] - 64, 64);
    if (tops[2] - tops[3] < 1e-4f) {
        double b0 = log((double)pr_lo) - log(-log((double)u_lo + 1e-20) + 1e-20);
        double b1 = log((double)pr_hi) - log(-log((double)u_hi + 1e-20) + 1e-20);
        int mcs[3];
#pragma unroll
        for (int pass = 0; pass < 3; ++pass) {
            double s; int si;
            if (b0 >= b1) { s = b0; si = lane; } else { s = b1; si = lane + 64; }
            for (int d = 32; d >= 1; d >>= 1) {
                double s2 = __shfl_xor(s, d, 64);
                int i2 = __shfl_xor(si, d, 64);
                if (s2 > s || (s2 == s && i2 < si)) { s = s2; si = i2; }
            }
            mcs[pass] = (si < 64) ? __shfl(mv_lo, si, 64) : __shfl(mv_hi, si - 64, 64);
            if (si == lane) b0 = -1.0e300;
            if (si == lane + 64) b1 = -1.0e300;
        }
        mc0 = mcs[0]; mc1 = mcs[1]; mc2 = mcs[2];
    }
    int rows[3] = { mc0, mc1, mc2 };

    // phase 3a: ISSUE all rows 0..2 loads + pos loads (independent, fill the memory queue)
    float vv[3][3];
    float px[3], py[3];
#pragma unroll
    for (int m = 0; m < 3; ++m) {
        size_t rbase = (browbase + rows[m]) * (size_t)CC;
        vv[m][0] = feat[rbase + lane];
        vv[m][1] = feat[rbase + lane + 64];
        vv[m][2] = feat[rbase + lane + 128];
        px[m] = pos[(browbase + rows[m]) * 2];
        py[m] = pos[(browbase + rows[m]) * 2 + 1];
    }

    // phase 3b: LayerNorm — row 3 first (data long resident), then rows 0..2
    float ng0 = norm_g[lane], ng1 = norm_g[lane + 64], ng2 = norm_g[lane + 128];
    float nb0 = norm_b[lane], nb1 = norm_b[lane + 64], nb2 = norm_b[lane + 128];
    float fgv[4][3];
    float prelx[4], prely[4];
    {
        float s = w30 + w31 + w32;
#pragma unroll
        for (int d = 32; d >= 1; d >>= 1) s += __shfl_xor(s, d, 64);
        float mu = s * (1.f / 192.f);
        float d0 = w30 - mu, d1 = w31 - mu, d2 = w32 - mu;
        float q = d0 * d0 + d1 * d1 + d2 * d2;
#pragma unroll
        for (int d = 32; d >= 1; d >>= 1) q += __shfl_xor(q, d, 64);
        float rstd = 1.f / sqrtf(q * (1.f / 192.f) + 1e-5f);
        fgv[3][0] = d0 * rstd * ng0 + nb0;
        fgv[3][1] = d1 * rstd * ng1 + nb1;
        fgv[3][2] = d2 * rstd * ng2 + nb2;
        prelx[3] = 0.f; prely[3] = 0.f;
    }
#pragma unroll
    for (int m = 0; m < 3; ++m) {
        float s = vv[m][0] + vv[m][1] + vv[m][2];
#pragma unroll
        for (int d = 32; d >= 1; d >>= 1) s += __shfl_xor(s, d, 64);
        float mu = s * (1.f / 192.f);
        float d0 = vv[m][0] - mu, d1 = vv[m][1] - mu, d2 = vv[m][2] - mu;
        float q = d0 * d0 + d1 * d1 + d2 * d2;
#pragma unroll
        for (int d = 32; d >= 1; d >>= 1) q += __shfl_xor(q, d, 64);
        float rstd = 1.f / sqrtf(q * (1.f / 192.f) + 1e-5f);
        fgv[m][0] = d0 * rstd * ng0 + nb0;
        fgv[m][1] = d1 * rstd * ng1 + nb1;
        fgv[m][2] = d2 * rstd * ng2 + nb2;
        prelx[m] = px[m] - pdx;
        prely[m] = py[m] - pdy;
    }

    // phase 4a: frelb build (this wave's private slice)
#pragma unroll
    for (int m = 0; m < 4; ++m)
#pragma unroll
        for (int jj = 0; jj < 3; ++jj)
            frelb[wave][m][lane + jj * 64] = f2bf(fgv[m][jj] - fgv[3][jj]);

    // phase 4b: pos MLP, 2 m-rows per lane
    {
        int kk = lane & 31;
        int mbase = lane >> 5;
#pragma unroll
        for (int t = 0; t < 2; ++t) {
            int m = mbase + 2 * t;
            float pxv = (m == 0) ? prelx[0] : (m == 1) ? prelx[1] : (m == 2) ? prelx[2] : prelx[3];
            float pyv = (m == 0) ? prely[0] : (m == 1) ? prely[1] : (m == 2) ? prely[2] : prely[3];
            float pre = pxv * w1W[kk] + pyv * w1W[32 + kk] + w1b[kk];
            float s = pre;
            for (int d = 16; d >= 1; d >>= 1) s += __shfl_xor(s, d, 64);
            float mu = s * (1.f / 32.f);
            float dv = pre - mu;
            float vs = dv * dv;
            for (int d = 16; d >= 1; d >>= 1) vs += __shfl_xor(vs, d, 64);
            float var = vs * (1.f / 32.f);
            float nv = dv / sqrtf(var + 1e-5f) * lng[kk] + lnb[kk];
            wsm[wave][m][kk] = gelu_fast(nv);
        }
    }

    // phase 5: gate MFMA — one wave does all 4 o-tiles (24 MFMAs)
    f32x4 acc[4];
#pragma unroll
    for (int w = 0; w < 4; ++w) acc[w] = (f32x4){0.f, 0.f, 0.f, 0.f};
#pragma unroll
    for (int ks = 0; ks < 6; ++ks) {
        short8 av;
        if (l15 < 4) av = *(const short8*)(&frelb[wave][l15][ks * 32 + l4 * 8]);
        else av = (short8){0,0,0,0,0,0,0,0};
#pragma unroll
        for (int w = 0; w < 4; ++w) {
            short8 bv = *(const short8*)(f1frag + ((size_t)(ks * 4 + w) * 64 + lane) * 8);
            acc[w] = __builtin_amdgcn_mfma_f32_16x16x32_bf16(av, bv, acc[w], 0, 0, 0);
        }
    }
    if (l4 == 0) {
#pragma unroll
        for (int w = 0; w < 4; ++w)
            *(f32x4*)(&hbuf[wave][w][l15 * 4]) = acc[w];
    }
    float fvs = 0.f;
#pragma unroll
    for (int w = 0; w < 4; ++w) {
        float hv = hbuf[wave][w][lane];              // o = w*16 + (lane>>2), m = lane&3
        int o = w * 16 + (lane >> 2);
        fvs += gelu_fast(hv + f1b[o]) * f2W[o];
    }
#pragma unroll
    for (int d = 4; d <= 32; d <<= 1) fvs += __shfl_xor(fvs, d, 64);
    fvs = 1.f / (1.f + __expf(-(fvs + f2b[0])));
    float fwv0 = __shfl(fvs, (lane & ~3) | 0, 64);
    float fwv1 = __shfl(fvs, (lane & ~3) | 1, 64);
    float fwv2 = __shfl(fvs, (lane & ~3) | 2, 64);
    float fwv3 = __shfl(fvs, (lane & ~3) | 3, 64);

    // phase 6: agg -> fp8 panels. lane owns c = lane + 64*i3; loop r (k = 8r..8r+7)
    {
        float g0[3], g1[3], g2[3], g3[3];
#pragma unroll
        for (int i3 = 0; i3 < 3; ++i3) {
            g0[i3] = fgv[0][i3] * fwv0;
            g1[i3] = fgv[1][i3] * fwv1;
            g2[i3] = fgv[2][i3] * fwv2;
            g3[i3] = fgv[3][i3] * fwv3;
        }
        int mrow = point & 127;
        uchar* ppan = agg + (size_t)(point >> 7) * PANEL + (size_t)mrow * 64;
#pragma unroll
        for (int r = 0; r < 4; ++r) {
            f32x4 wq0a = *(const f32x4*)(&wsm[wave][0][8 * r]);
            f32x4 wq0b = *(const f32x4*)(&wsm[wave][0][8 * r + 4]);
            f32x4 wq1a = *(const f32x4*)(&wsm[wave][1][8 * r]);
            f32x4 wq1b = *(const f32x4*)(&wsm[wave][1][8 * r + 4]);
            f32x4 wq2a = *(const f32x4*)(&wsm[wave][2][8 * r]);
            f32x4 wq2b = *(const f32x4*)(&wsm[wave][2][8 * r + 4]);
            f32x4 wq3a = *(const f32x4*)(&wsm[wave][3][8 * r]);
            f32x4 wq3b = *(const f32x4*)(&wsm[wave][3][8 * r + 4]);
            int gp = (r ^ ((mrow >> 1) & 3)) << 4;
#pragma unroll
            for (int i3 = 0; i3 < 3; ++i3) {
                int c = lane + 64 * i3;
                f32x4 va = wq0a * g0[i3];
                va += wq1a * g1[i3];
                va += wq2a * g2[i3];
                va += wq3a * g3[i3];
                f32x4 vb = wq0b * g0[i3];
                vb += wq1b * g1[i3];
                vb += wq2b * g2[i3];
                vb += wq3b * g3[i3];
                uint32 w0_ = __builtin_amdgcn_cvt_pk_fp8_f32(va[0], va[1], 0, false);
                w0_ = __builtin_amdgcn_cvt_pk_fp8_f32(va[2], va[3], w0_, true);
                uint32 w1_ = __builtin_amdgcn_cvt_pk_fp8_f32(vb[0], vb[1], 0, false);
                w1_ = __builtin_amdgcn_cvt_pk_fp8_f32(vb[2], vb[3], w1_, true);
                *(u32x2*)(ppan + (size_t)(c >> 1) * 8192 + gp + 8 * (c & 1)) = (u32x2){w0_, w1_};
            }
        }
    }
}

// ---- GEMM: MX-scaled fp8 (scale=1.0), 32x32x64, BN=384, pre-tiled panels, 4-buf depth-3 ----
__global__ __launch_bounds__(256, 1) void k_gemm(const uchar* __restrict__ A,
    const uchar* __restrict__ BT, const float* __restrict__ bias,
    float* __restrict__ out, int p0)
{
    __shared__ __align__(16) uchar lds[4][32768];   // per buf: A[128][64] @0, B[384][64] @8192
    int tid = threadIdx.x;
    int wave = tid >> 6, lane = tid & 63;
    int l31 = lane & 31, h = lane >> 5;
    int m0 = blockIdx.x * 128;

    const uchar* Apan = A + ((size_t)(p0 >> 7) + blockIdx.x) * PANEL;

    f32x16 acc[4][3];
#pragma unroll
    for (int a = 0; a < 4; ++a)
#pragma unroll
        for (int bb = 0; bb < 3; ++bb)
#pragma unroll
            for (int e = 0; e < 16; ++e) acc[a][bb][e] = 0.f;

    auto stage = [&](int buf, int t) {
        const uchar* as = Apan + (size_t)t * 8192 + tid * 16;
        const uchar* bs = BT + (size_t)t * 24576 + tid * 16;
        uchar* ld = &lds[buf][0] + tid * 16;
#pragma unroll
        for (int i = 0; i < 2; ++i) gld16(as + i * 4096, ld + i * 4096);
#pragma unroll
        for (int i = 0; i < 6; ++i) gld16(bs + i * 4096, ld + 8192 + i * 4096);
    };

    int fsw = (l31 >> 1) & 3;
    int g0 = ((2 * h) ^ fsw) * 16;
    int g1 = ((2 * h + 1) ^ fsw) * 16;
    auto compute = [&](int t) {
        const uchar* Ab = &lds[t & 3][0];
        const uchar* Bb = Ab + 8192;
        union V8 { i64x2 hh[2]; i32x8 v; };
        V8 av[4], bv[3];
#pragma unroll
        for (int a = 0; a < 4; ++a) {
            int ro = (32 * a + l31) * 64;
            av[a].hh[0] = *(const i64x2*)(Ab + ro + g0);
            av[a].hh[1] = *(const i64x2*)(Ab + ro + g1);
        }
#pragma unroll
        for (int bb = 0; bb < 3; ++bb) {
            int ro = (wave * 96 + 32 * bb + l31) * 64;
            bv[bb].hh[0] = *(const i64x2*)(Bb + ro + g0);
            bv[bb].hh[1] = *(const i64x2*)(Bb + ro + g1);
        }
#pragma unroll
        for (int a = 0; a < 4; ++a)
#pragma unroll
            for (int bb = 0; bb < 3; ++bb)
                acc[a][bb] = __builtin_amdgcn_mfma_scale_f32_32x32x64_f8f6f4(
                    av[a].v, bv[bb].v, acc[a][bb], 0, 0, 0, 0x7F, 0, 0x7F);
    };

    // depth-3 pipeline, 8 gld16/thread/stage -> vmcnt(16) drains the oldest stage
    stage(0, 0);
    stage(1, 1);
    stage(2, 2);
    for (int t = 0; t < 94; ++t) {
        asm volatile("s_waitcnt vmcnt(16)" ::: "memory");
        __builtin_amdgcn_s_barrier();
        __builtin_amdgcn_sched_barrier(0);
        if (t < 93) stage((t + 3) & 3, t + 3);
        compute(t);
    }
    asm volatile("s_waitcnt vmcnt(8)" ::: "memory");
    __builtin_amdgcn_s_barrier();
    __builtin_amdgcn_sched_barrier(0);
    compute(94);
    asm volatile("s_waitcnt vmcnt(0)" ::: "memory");
    __builtin_amdgcn_s_barrier();
    __builtin_amdgcn_sched_barrier(0);
    compute(95);

    // C layout (32x32): col = lane&31, row = (reg&3) + 8*(reg>>2) + 4*(lane>>5)
#pragma unroll
    for (int a = 0; a < 4; ++a)
#pragma unroll
        for (int bb = 0; bb < 3; ++bb)
#pragma unroll
            for (int reg = 0; reg < 16; ++reg) {
                int rowm = (reg & 3) + 8 * (reg >> 2) + 4 * h;
                int rr = m0 + 32 * a + rowm;
                int cc = wave * 96 + 32 * bb + l31;
                out[(size_t)(p0 + rr) * 384 + cc] = acc[a][bb][reg] + bias[cc];
            }
}

extern "C" void kernel_launch(void* const* d_in, const int* in_sizes, int n_in,
                              void* d_out, int out_size, void* d_ws, size_t ws_size,
                              hipStream_t stream)
{
    const float* pos      = (const float*)d_in[0];
    const float* feat     = (const float*)d_in[1];
    const float* maskp    = (const float*)d_in[2];
    const int*   massign  = (const int*)d_in[4];
    const int*   memidx   = (const int*)d_in[5];
    const float* cmaskp   = (const float*)d_in[9];
    const float* norm_g   = (const float*)d_in[10];
    const float* norm_b   = (const float*)d_in[11];
    const float* w1W      = (const float*)d_in[12];
    const float* w1b      = (const float*)d_in[13];
    const float* lng      = (const float*)d_in[14];
    const float* lnb      = (const float*)d_in[15];
    const float* f1W      = (const float*)d_in[16];
    const float* f1b      = (const float*)d_in[17];
    const float* f2W      = (const float*)d_in[18];
    const float* f2b      = (const float*)d_in[19];
    const float* linW     = (const float*)d_in[20];
    const float* linb     = (const float*)d_in[21];

    char* ws = (char*)d_ws;
    int* img         = (int*)(ws);                      //    401,408 B
    int* idxa        = (int*)(ws + 401408);             //    100,352 B
    uchar* linT      = (uchar*)(ws + 501760);           //  2,359,296 B (fp8, tiled)
    ushort_t* f1frag = (ushort_t*)(ws + 2861056);       //     24,576 B
    uchar* agg       = (uchar*)(ws + 2885632);          // up to 154,140,672 B (fp8, panels)

    size_t avail = ws_size > 2885632 ? ws_size - 2885632 : 0;
    long long slabM = (long long)(avail / 6144);
    slabM &= ~127LL;
    if (slabM > TOTPTS) slabM = TOTPTS;
    if (slabM < 128) slabM = 128;

    hipMemsetAsync(img, 0, 401408, stream);
    k_scatter<<<392, 256, 0, stream>>>(pos, img);
    k_down<<<98, 256, 0, stream>>>(img, idxa);
    k_linT<<<dim3(96, 6), 256, 0, stream>>>(linW, linT);
    k_prep<<<48, 256, 0, stream>>>(f1W, f1frag);

    float* outF = (float*)d_out;
    for (int p0 = 0; p0 < TOTPTS; p0 += (int)slabM) {
        int cnt = TOTPTS - p0; if (cnt > (int)slabM) cnt = (int)slabM;
        k_point<<<cnt / 4, 256, 0, stream>>>(pos, feat, maskp, massign, memidx, cmaskp, idxa, f1frag,
                norm_g, norm_b, w1W, w1b, lng, lnb, f1b, f2W, f2b, agg, outF, p0);
        k_gemm<<<cnt / 128, 256, 0, stream>>>(agg, linT, linb, outF + OUT_FEAT_OFF, p0);
    }
}